// Round 10
// baseline (209.715 us; speedup 1.0000x reference)
//
#include <hip/hip_runtime.h>

typedef unsigned short u16;
typedef __bf16 bf16x8 __attribute__((ext_vector_type(8)));
typedef float f32x4 __attribute__((ext_vector_type(4)));
typedef unsigned short u16x8 __attribute__((ext_vector_type(8)));

#define QKV_N 5120
#define SEQ 2048
#define ATTN_K 4096
#define KPAD 2944   // 2880 padded to 46*64
#define SCALE 0.125f
#define NEGINF -1e30f

__device__ __forceinline__ u16 f2bf(float f) {
  unsigned int u = __builtin_bit_cast(unsigned int, f);
  u = (u + 0x7FFFu + ((u >> 16) & 1u)) >> 16;
  return (u16)u;
}
__device__ __forceinline__ float bf2f(u16 u) {
  unsigned int x = ((unsigned int)u) << 16;
  return __builtin_bit_cast(float, x);
}

#define MFMA16(a, b, c) __builtin_amdgcn_mfma_f32_16x16x32_bf16((a), (b), (c), 0, 0, 0)

// async global->LDS, 16B per lane; LDS dest = wave-uniform base + lane*16
__device__ __forceinline__ void gl_lds16(const u16* g, u16* l) {
  __builtin_amdgcn_global_load_lds(
      (const __attribute__((address_space(1))) unsigned int*)(const void*)g,
      (__attribute__((address_space(3))) unsigned int*)(void*)l, 16, 0, 0);
}

// fragment read from [rows][32k] half-tile (64B rows); swizzle key (row>>1)&3
__device__ __forceinline__ bf16x8 fragrd(const u16* base, int row, int rb) {
  return *(const bf16x8*)((const char*)(base + row * 32) + rb);
}

// ---------------- RoPE table: tab[s*32+i] = {cos, sin} ----------------
__global__ __launch_bounds__(256) void k_rope_table(const int* __restrict__ pos,
                                                    float2* __restrict__ tab) {
  int t = blockIdx.x * 256 + threadIdx.x;  // 65536 = 2048*32
  int s = t >> 5, i = t & 31;
  float freq = powf(150000.0f, -(float)i * (1.0f / 32.0f));
  float ang = (float)pos[s] * freq;
  float sv, cv;
  sincosf(ang, &sv, &cv);
  tab[t] = make_float2(cv, sv);
}

// ---------------- f32 -> bf16 convert with K-pad: out [2048][2944] ----------------
__global__ __launch_bounds__(256) void k_convert_pad(const float* __restrict__ in,
                                                     u16* __restrict__ out) {
  int i = blockIdx.x * 256 + threadIdx.x;  // per 4 out elems; 2048*736 total
  int r = i / 736, c4 = i - r * 736;
  if (r >= 2048) return;
  ushort4 o = {0, 0, 0, 0};
  if (c4 < 720) {
    float4 v = *(const float4*)(in + (size_t)r * 2880 + c4 * 4);
    o.x = f2bf(v.x); o.y = f2bf(v.y); o.z = f2bf(v.z); o.w = f2bf(v.w);
  }
  ((ushort4*)out)[(size_t)r * 736 + c4] = o;
}

// ------ transpose+convert: in f32 [Kin][Nd] -> out bf16 [Npad][Kout], zero-padded ------
__global__ __launch_bounds__(256) void k_transpose(const float* __restrict__ in,
                                                   u16* __restrict__ out,
                                                   int Kin, int Kout, int Nd, int Npad) {
  __shared__ float tile[32][33];
  int n0 = blockIdx.x * 32, k0 = blockIdx.y * 32;
  int c = threadIdx.x & 31, r0 = threadIdx.x >> 5;
#pragma unroll
  for (int j = 0; j < 4; j++) {
    int r = r0 + j * 8;
    float v = 0.f;
    if (n0 + c < Nd && k0 + r < Kin) v = in[(size_t)(k0 + r) * Nd + n0 + c];
    tile[r][c] = v;
  }
  __syncthreads();
#pragma unroll
  for (int j = 0; j < 4; j++) {
    int rr = r0 + j * 8;  // local n
    int n = n0 + rr;
    if (n < Npad) out[(size_t)n * Kout + k0 + c] = f2bf(tile[c][rr]);
  }
}

// ======== GEMM1: 128x160 tiles, grid 512 (2 blocks/CU), BK=64, 4-phase schedule ======
// A [2048][2944] bf16, B [5120][2944] bf16 (B^T), out qkv bf16 [2048][5120], bias only.
__global__ __launch_bounds__(256, 2) void k_gemm1(const u16* __restrict__ Ag,
                                                  const u16* __restrict__ Bg,
                                                  const float* __restrict__ bias,
                                                  u16* __restrict__ C) {
  __shared__ u16 lds_[2][18432];
  u16* L = &lds_[0][0];
  const int tid = threadIdx.x;
  const int lane = tid & 63, wave = tid >> 6;
  const int wm = wave >> 1, wn = wave & 1;
  const int lr = lane & 15, lg = lane >> 4;
  const int bid = blockIdx.x;
  const int sb = (bid & 7) * 64 + (bid >> 3);  // 512 = 8 XCD x 64
  const int m0 = (sb >> 5) * 128, n0 = (sb & 31) * 160;

  f32x4 acc[4][5] = {};
  bf16x8 Bf[5], Af0, Af1;

  const int rb = (lg * 16) ^ (((lr >> 1) & 3) << 4);      // frag-read swizzled byte off
  const int arow = tid >> 2;                              // A staging row within 64-round
  const int axs = ((tid & 3) ^ ((tid >> 3) & 3)) << 3;    // A pre-swizzled chunk (elems)

  // B staging: 5 rounds per tile over linear [kh0 5120 | kh1 5120] region
  size_t boff[5];
#pragma unroll
  for (int r_ = 0; r_ < 5; r_++) {
    int e = r_ * 2048 + tid * 8;
    int bkh = (e >= 5120) ? 1 : 0;
    int re = e - bkh * 5120;
    int brow = re >> 5;
    int bch = (re >> 3) & 3;
    int bps = bch ^ ((brow >> 1) & 3);
    boff[r_] = (size_t)(n0 + brow) * KPAD + bkh * 32 + bps * 8;
  }

#define STA(b, kh, kt, r_)                                                      \
  gl_lds16(Ag + (size_t)(m0 + (r_) * 64 + arow) * KPAD + (kt) + (kh) * 32 + axs, \
           L + (b) * 18432 + (kh) * 4096 + (r_) * 2048 + wave * 512)
#define STB(b, kt, r_)                                                          \
  gl_lds16(Bg + boff[r_] + (kt), L + (b) * 18432 + 8192 + (r_) * 2048 + wave * 512)
#define RDB(b, kh)                                                              \
  { _Pragma("unroll") for (int nf = 0; nf < 5; nf++)                            \
      Bf[nf] = fragrd(L + (b) * 18432 + 8192 + (kh) * 5120,                     \
                      wn * 80 + nf * 16 + lr, rb); }
#define RDA(b, kh, mf0_)                                                        \
  { Af0 = fragrd(L + (b) * 18432 + (kh) * 4096, wm * 64 + (mf0_) * 16 + lr, rb); \
    Af1 = fragrd(L + (b) * 18432 + (kh) * 4096, wm * 64 + ((mf0_) + 1) * 16 + lr, rb); }
#define MM(ma, mb)                                                              \
  { __builtin_amdgcn_s_setprio(1);                                              \
    _Pragma("unroll") for (int nf = 0; nf < 5; nf++) {                          \
      acc[ma][nf] = MFMA16(Af0, Bf[nf], acc[ma][nf]);                           \
      acc[mb][nf] = MFMA16(Af1, Bf[nf], acc[mb][nf]); }                         \
    __builtin_amdgcn_s_setprio(0); }
#define BAR __builtin_amdgcn_s_barrier();
#define VM4 asm volatile("s_waitcnt vmcnt(4)" ::: "memory");
#define VM0 asm volatile("s_waitcnt vmcnt(0)" ::: "memory");

  // prologue: tile 0 -> buf0 (ops 1-9); certify ops 1-5 (A-kh0 + B r0..r2)
  STA(0, 0, 0, 0); STA(0, 0, 0, 1);
  STB(0, 0, 0); STB(0, 0, 1); STB(0, 0, 2); STB(0, 0, 3); STB(0, 0, 4);
  STA(0, 1, 0, 0); STA(0, 1, 0, 1);
  VM4 BAR

  for (int t = 0; t < 46; t++) {
    const int b = t & 1, nb = b ^ 1;
    const int kt1 = (t + 1) * 64;
    const bool st = (t < 45);
    RDB(b, 0) RDA(b, 0, 0)
    if (st) { STA(nb, 0, kt1, 0); STA(nb, 0, kt1, 1); STB(nb, kt1, 0); }
    BAR MM(0, 1) BAR
    RDA(b, 0, 2)
    if (st) { STB(nb, kt1, 1); STB(nb, kt1, 2); VM4 } else { VM0 }
    BAR MM(2, 3) BAR
    RDB(b, 1) RDA(b, 1, 0)
    if (st) { STB(nb, kt1, 3); STB(nb, kt1, 4); }
    BAR MM(0, 1) BAR
    RDA(b, 1, 2)
    if (st) { STA(nb, 1, kt1, 0); STA(nb, 1, kt1, 1); VM4 }
    BAR MM(2, 3) BAR
  }
#undef STA
#undef STB
#undef RDB
#undef RDA
#undef MM

  // ---- epilogue: bias, bf16 store ----
#pragma unroll
  for (int mf = 0; mf < 4; mf++)
#pragma unroll
    for (int nf = 0; nf < 5; nf++) {
      int col = n0 + wn * 80 + nf * 16 + lr;
      float bv = bias[col];
#pragma unroll
      for (int rg = 0; rg < 4; rg++) {
        int row = m0 + wm * 64 + mf * 16 + lg * 4 + rg;
        C[(size_t)row * QKV_N + col] = f2bf(acc[mf][nf][rg] + bv);
      }
    }
}

// ======== GEMM2: 128x96 tiles, grid 512 (2 blocks/CU), BK=64, 4-phase schedule ======
// A = attn bf16 [2048][4096], B = woT bf16 [3072][4096] (padded), C f32 [2048][2880].
// LDS/buf: A[2kh][128][32] (16KB) + B[2kh][96][32] (12KB) = 28KB; dbuf 56KB.
// Stage plan/tile (7 ops): [a0,a1,b0 | b1,b2 | a2 | a3]; vmcnt(5)@p1, vmcnt(2)@p3.
// Invariant entering each tile: [a2,a3] in flight, rest certified.
__global__ __launch_bounds__(256, 2) void k_gemm2(const u16* __restrict__ Ag,
                                                  const u16* __restrict__ Bg,
                                                  const float* __restrict__ bias,
                                                  float* __restrict__ C) {
  __shared__ u16 lds_[2][14336];
  u16* L = &lds_[0][0];
  const int tid = threadIdx.x;
  const int lane = tid & 63, wave = tid >> 6;
  const int wm = wave >> 1, wn = wave & 1;
  const int lr = lane & 15, lg = lane >> 4;
  const int bid = blockIdx.x;
  const int sb = (bid & 7) * 64 + (bid >> 3);  // 512 = 8 XCD x 64
  const int m0 = (sb >> 5) * 128, n0 = (sb & 31) * 96;

  f32x4 acc[4][3] = {};
  bf16x8 Bf[3], Af0, Af1;

  const int rb = (lg * 16) ^ (((lr >> 1) & 3) << 4);
  const int arow = tid >> 2;
  const int axs = ((tid & 3) ^ ((tid >> 3) & 3)) << 3;

  // B staging: 3 rounds over linear [kh0 3072 | kh1 3072] region (u16 elems)
  size_t boff[3];
#pragma unroll
  for (int r_ = 0; r_ < 3; r_++) {
    int e = r_ * 2048 + tid * 8;
    int bkh = (e >= 3072) ? 1 : 0;
    int re = e - bkh * 3072;
    int brow = re >> 5;
    int bch = (re >> 3) & 3;
    int bps = bch ^ ((brow >> 1) & 3);
    boff[r_] = (size_t)(n0 + brow) * ATTN_K + bkh * 32 + bps * 8;
  }

#define STA2(b, kh, kt, r_)                                                     \
  gl_lds16(Ag + (size_t)(m0 + (r_) * 64 + arow) * ATTN_K + (kt) + (kh) * 32 + axs, \
           L + (b) * 14336 + (kh) * 4096 + (r_) * 2048 + wave * 512)
#define STB2(b, kt, r_)                                                         \
  gl_lds16(Bg + boff[r_] + (kt), L + (b) * 14336 + 8192 + (r_) * 2048 + wave * 512)
#define RDB2(b, kh)                                                             \
  { _Pragma("unroll") for (int nf = 0; nf < 3; nf++)                            \
      Bf[nf] = fragrd(L + (b) * 14336 + 8192 + (kh) * 3072,                     \
                      wn * 48 + nf * 16 + lr, rb); }
#define RDA2(b, kh, mf0_)                                                       \
  { Af0 = fragrd(L + (b) * 14336 + (kh) * 4096, wm * 64 + (mf0_) * 16 + lr, rb); \
    Af1 = fragrd(L + (b) * 14336 + (kh) * 4096, wm * 64 + ((mf0_) + 1) * 16 + lr, rb); }
#define MM2(ma, mb)                                                             \
  { __builtin_amdgcn_s_setprio(1);                                              \
    _Pragma("unroll") for (int nf = 0; nf < 3; nf++) {                          \
      acc[ma][nf] = MFMA16(Af0, Bf[nf], acc[ma][nf]);                           \
      acc[mb][nf] = MFMA16(Af1, Bf[nf], acc[mb][nf]); }                         \
    __builtin_amdgcn_s_setprio(0); }
#define VM5 asm volatile("s_waitcnt vmcnt(5)" ::: "memory");
#define VM2 asm volatile("s_waitcnt vmcnt(2)" ::: "memory");

  // prologue: tile 0 -> buf0, issue order [a0,a1,b0,b1,b2,a2,a3]; certify first 5
  STA2(0, 0, 0, 0); STA2(0, 0, 0, 1);
  STB2(0, 0, 0); STB2(0, 0, 1); STB2(0, 0, 2);
  STA2(0, 1, 0, 0); STA2(0, 1, 0, 1);
  VM2 BAR

  for (int t = 0; t < 64; t++) {
    const int b = t & 1, nb = b ^ 1;
    const int kt1 = (t + 1) * 64;
    const bool st = (t < 63);
    // p0: reads B[kh0] (b0,b1) + A[kh0] mf0-1; stage a0',a1',b0'
    RDB2(b, 0) RDA2(b, 0, 0)
    if (st) { STA2(nb, 0, kt1, 0); STA2(nb, 0, kt1, 1); STB2(nb, kt1, 0); }
    BAR MM2(0, 1) BAR
    // p1: A[kh0] mf2-3; stage b1',b2'; certify a2,a3 (cur tile, staged prev tile)
    RDA2(b, 0, 2)
    if (st) { STB2(nb, kt1, 1); STB2(nb, kt1, 2); VM5 } else { VM0 }
    BAR MM2(2, 3) BAR
    // p2: B[kh1] (b1,b2) + A[kh1] mf0-1; stage a2'
    RDB2(b, 1) RDA2(b, 1, 0)
    if (st) { STA2(nb, 1, kt1, 0); }
    BAR MM2(0, 1) BAR
    // p3: A[kh1] mf2-3; stage a3'; certify a0',a1',b0',b1',b2' for next tile
    RDA2(b, 1, 2)
    if (st) { STA2(nb, 1, kt1, 1); VM2 }
    BAR MM2(2, 3) BAR
  }
#undef STA2
#undef STB2
#undef RDB2
#undef RDA2
#undef MM2
#undef VM5
#undef VM2
#undef BAR
#undef VM4
#undef VM0

  // ---- epilogue: bias + f32 store (guard padded cols) ----
#pragma unroll
  for (int mf = 0; mf < 4; mf++)
#pragma unroll
    for (int nf = 0; nf < 3; nf++) {
      int col = n0 + wn * 48 + nf * 16 + lr;
      if (col < 2880) {
        float bv = bias[col];
#pragma unroll
        for (int rg = 0; rg < 4; rg++) {
          int row = m0 + wm * 64 + mf * 16 + lg * 4 + rg;
          C[(size_t)row * 2880 + col] = acc[mf][nf][rg] + bv;
        }
      }
    }
}

// -------- sliding-window attention with sinks; RoPE fused on Q (in-reg) and K (staging)
__global__ __launch_bounds__(512, 2) void k_attn(const u16* __restrict__ qkv,
                                                 const float* __restrict__ sinks,
                                                 const float2* __restrict__ tab,
                                                 u16* __restrict__ out) {
  __shared__ u16 Klds[160 * 64];
  __shared__ u16 Vt[64 * 168];
  __shared__ u16 Pslab[8 * 32 * 40];
  const int hk = blockIdx.y;
  const int s0 = blockIdx.x * 32;
  const int kb = s0 - 127;
  const int tid = threadIdx.x;
  const int lane = tid & 63, w = tid >> 6;
  const int lr = lane & 15, lg = lane >> 4;

  for (int u = tid; u < 160 * 4; u += 512) {
    int key = u >> 2, c = u & 3;
    int kidx = kb + key;
    u16x8 v1 = {0, 0, 0, 0, 0, 0, 0, 0}, v2 = v1;
    if (kidx >= 0 && kidx < SEQ) {
      const u16* base = qkv + (size_t)kidx * QKV_N + 4096 + hk * 64;
      u16x8 x1 = *(const u16x8*)(base + c * 8);
      u16x8 x2 = *(const u16x8*)(base + 32 + c * 8);
      const float2* cs = tab + (size_t)kidx * 32 + c * 8;
#pragma unroll
      for (int j = 0; j < 8; j++) {
        float f1 = bf2f(x1[j]), f2 = bf2f(x2[j]);
        float2 t = cs[j];
        v1[j] = f2bf(f1 * t.x - f2 * t.y);
        v2[j] = f2bf(f2 * t.x + f1 * t.y);
      }
    }
    int o1 = (key * 128 + c * 16) ^ ((key & 7) << 4);
    int o2 = (key * 128 + (c + 4) * 16) ^ ((key & 7) << 4);
    *(u16x8*)((char*)Klds + o1) = v1;
    *(u16x8*)((char*)Klds + o2) = v2;
  }
  for (int e4 = tid; e4 < 160 * 16; e4 += 512) {
    int key = e4 >> 4, d0 = (e4 & 15) * 4;
    int kidx = kb + key;
    ushort4 v = {0, 0, 0, 0};
    if (kidx >= 0 && kidx < SEQ)
      v = *(const ushort4*)(qkv + (size_t)kidx * QKV_N + 4608 + hk * 64 + d0);
    Vt[(d0 + 0) * 168 + key] = v.x;
    Vt[(d0 + 1) * 168 + key] = v.y;
    Vt[(d0 + 2) * 168 + key] = v.z;
    Vt[(d0 + 3) * 168 + key] = v.w;
  }

  const int head = hk * 8 + w;
  bf16x8 qf[2][2];
#pragma unroll
  for (int rt = 0; rt < 2; rt++) {
    int s = s0 + rt * 16 + lr;
    const u16* base = qkv + (size_t)s * QKV_N + head * 64 + lg * 8;
    u16x8 r0 = *(const u16x8*)(base);
    u16x8 r1 = *(const u16x8*)(base + 32);
    const float2* cs = tab + (size_t)s * 32 + lg * 8;
    u16x8 y0, y1;
#pragma unroll
    for (int j = 0; j < 8; j++) {
      float f1 = bf2f(r0[j]), f2 = bf2f(r1[j]);
      float2 t = cs[j];
      y0[j] = f2bf(f1 * t.x - f2 * t.y);
      y1[j] = f2bf(f2 * t.x + f1 * t.y);
    }
    qf[rt][0] = __builtin_bit_cast(bf16x8, y0);
    qf[rt][1] = __builtin_bit_cast(bf16x8, y1);
  }
  __syncthreads();

  f32x4 sc[2][10];
  f32x4 zz = {0.f, 0.f, 0.f, 0.f};
#pragma unroll
  for (int rt = 0; rt < 2; rt++)
#pragma unroll
    for (int nt = 0; nt < 10; nt++) sc[rt][nt] = zz;
#pragma unroll
  for (int nt = 0; nt < 10; nt++) {
    int key = nt * 16 + lr;
#pragma unroll
    for (int ks = 0; ks < 2; ks++) {
      int off = (key * 128 + ks * 64 + lg * 16) ^ ((key & 7) << 4);
      bf16x8 kf = *(const bf16x8*)((const char*)Klds + off);
      sc[0][nt] = MFMA16(qf[0][ks], kf, sc[0][nt]);
      sc[1][nt] = MFMA16(qf[1][ks], kf, sc[1][nt]);
    }
  }

#pragma unroll
  for (int rt = 0; rt < 2; rt++)
#pragma unroll
    for (int nt = 0; nt < 10; nt++)
#pragma unroll
      for (int rg = 0; rg < 4; rg++) {
        int qq = rt * 16 + lg * 4 + rg;
        int j = nt * 16 + lr;
        bool valid = (j >= qq) && (j <= qq + 127) && ((kb + j) >= 0);
        sc[rt][nt][rg] = valid ? sc[rt][nt][rg] * SCALE : NEGINF;
      }

  const float sink = sinks[head];
  float den[2][4];
#pragma unroll
  for (int rt = 0; rt < 2; rt++)
#pragma unroll
    for (int rg = 0; rg < 4; rg++) {
      float m = NEGINF;
#pragma unroll
      for (int nt = 0; nt < 10; nt++) m = fmaxf(m, sc[rt][nt][rg]);
#pragma unroll
      for (int x = 1; x < 16; x <<= 1) m = fmaxf(m, __shfl_xor(m, x, 64));
      m = fmaxf(m, sink);
      float sum = 0.f;
#pragma unroll
      for (int nt = 0; nt < 10; nt++) {
        float p = __expf(sc[rt][nt][rg] - m);
        sc[rt][nt][rg] = p;
        sum += p;
      }
#pragma unroll
      for (int x = 1; x < 16; x <<= 1) sum += __shfl_xor(sum, x, 64);
      den[rt][rg] = sum + __expf(sink - m);
    }

  f32x4 oacc[2][4];
#pragma unroll
  for (int rt = 0; rt < 2; rt++)
#pragma unroll
    for (int dn = 0; dn < 4; dn++) oacc[rt][dn] = zz;
  u16* slab = &Pslab[w * 32 * 40];
#pragma unroll
  for (int kt = 0; kt < 5; kt++) {
#pragma unroll
    for (int rt = 0; rt < 2; rt++)
#pragma unroll
      for (int j2 = 0; j2 < 2; j2++)
#pragma unroll
        for (int rg = 0; rg < 4; rg++)
          slab[(rt * 16 + lg * 4 + rg) * 40 + j2 * 16 + lr] = f2bf(sc[rt][kt * 2 + j2][rg]);
    asm volatile("s_waitcnt lgkmcnt(0)" ::: "memory");
    __builtin_amdgcn_sched_barrier(0);
    bf16x8 pf0 = *(const bf16x8*)&slab[lr * 40 + lg * 8];
    bf16x8 pf1 = *(const bf16x8*)&slab[(16 + lr) * 40 + lg * 8];
#pragma unroll
    for (int dn = 0; dn < 4; dn++) {
      bf16x8 vf = *(const bf16x8*)&Vt[(dn * 16 + lr) * 168 + kt * 32 + lg * 8];
      oacc[0][dn] = MFMA16(pf0, vf, oacc[0][dn]);
      oacc[1][dn] = MFMA16(pf1, vf, oacc[1][dn]);
    }
  }

#pragma unroll
  for (int rt = 0; rt < 2; rt++)
#pragma unroll
    for (int dn = 0; dn < 4; dn++)
#pragma unroll
      for (int rg = 0; rg < 4; rg++) {
        int s = s0 + rt * 16 + lg * 4 + rg;
        float val = oacc[rt][dn][rg] / den[rt][rg];
        out[(size_t)s * ATTN_K + head * 64 + dn * 16 + lr] = f2bf(val);
      }
}

extern "C" void kernel_launch(void* const* d_in, const int* in_sizes, int n_in,
                              void* d_out, int out_size, void* d_ws, size_t ws_size,
                              hipStream_t stream) {
  const float* hs = (const float*)d_in[0];
  const int* pos = (const int*)d_in[1];
  const float* wqkv = (const float*)d_in[2];
  const float* bqkv = (const float*)d_in[3];
  const float* wo = (const float*)d_in[4];
  const float* bo = (const float*)d_in[5];
  const float* sinks = (const float*)d_in[6];
  float* out = (float*)d_out;

  char* ws = (char*)d_ws;
  u16* qkvb = (u16*)(ws + 0);               // 2048*5120*2 = 20,971,520 (bf16, un-roped)
  u16* hsb = (u16*)(ws + 41943040);         // 2048*2944*2 = 12,058,624
  u16* wqkvT = (u16*)(ws + 54001664);       // 5120*2944*2 = 30,146,560 -> ends 84,148,224
  u16* attnb = (u16*)(ws + 41943040);       // 2048*4096*2 (aliases dead hsb/wqkvT)
  u16* woT = (u16*)(ws + 84148224);         // 3072*4096*2 = 25,165,824 -> ends 109,314,048
  float2* tab = (float2*)(ws + 109314048);  // 2048*32*8   = 524,288

  k_rope_table<<<256, 256, 0, stream>>>(pos, tab);
  k_convert_pad<<<5888, 256, 0, stream>>>(hs, hsb);
  k_transpose<<<dim3(160, 92), 256, 0, stream>>>(wqkv, wqkvT, 2880, KPAD, 5120, 5120);
  k_transpose<<<dim3(96, 128), 256, 0, stream>>>(wo, woT, 4096, 4096, 2880, 3072);
  k_gemm1<<<512, 256, 0, stream>>>(hsb, wqkvT, bqkv, qkvb);
  k_attn<<<dim3(64, 8), 512, 0, stream>>>(qkvb, sinks, tab, attnb);
  k_gemm2<<<512, 256, 0, stream>>>(attnb, woT, bo, out);
}

// Round 11
// 202.913 us; speedup vs baseline: 1.0335x; 1.0335x over previous
//
#include <hip/hip_runtime.h>

typedef unsigned short u16;
typedef __bf16 bf16x8 __attribute__((ext_vector_type(8)));
typedef float f32x4 __attribute__((ext_vector_type(4)));
typedef unsigned short u16x8 __attribute__((ext_vector_type(8)));

#define QKV_N 5120
#define SEQ 2048
#define ATTN_K 4096
#define KPAD 2944   // 2880 padded to 46*64
#define SCALE 0.125f
#define NEGINF -1e30f

__device__ __forceinline__ u16 f2bf(float f) {
  unsigned int u = __builtin_bit_cast(unsigned int, f);
  u = (u + 0x7FFFu + ((u >> 16) & 1u)) >> 16;
  return (u16)u;
}
__device__ __forceinline__ float bf2f(u16 u) {
  unsigned int x = ((unsigned int)u) << 16;
  return __builtin_bit_cast(float, x);
}

#define MFMA16(a, b, c) __builtin_amdgcn_mfma_f32_16x16x32_bf16((a), (b), (c), 0, 0, 0)

// async global->LDS, 16B per lane; LDS dest = wave-uniform base + lane*16
__device__ __forceinline__ void gl_lds16(const u16* g, u16* l) {
  __builtin_amdgcn_global_load_lds(
      (const __attribute__((address_space(1))) unsigned int*)(const void*)g,
      (__attribute__((address_space(3))) unsigned int*)(void*)l, 16, 0, 0);
}

// fragment read from [rows][32k] half-tile (64B rows); swizzle key (row>>1)&3
__device__ __forceinline__ bf16x8 fragrd(const u16* base, int row, int rb) {
  return *(const bf16x8*)((const char*)(base + row * 32) + rb);
}

// legacy frag read for GEMM2's [rows][64k] swizzled tile (128B rows)
__device__ __forceinline__ bf16x8 lds_frag(const u16* mat, int row, int kh, int lg) {
  int off = row * 128 + ((kh * 64 + lg * 16) ^ ((row & 7) << 4));
  return *(const bf16x8*)((const char*)mat + off);
}

// ---------------- RoPE table: tab[s*32+i] = {cos, sin} ----------------
__global__ __launch_bounds__(256) void k_rope_table(const int* __restrict__ pos,
                                                    float2* __restrict__ tab) {
  int t = blockIdx.x * 256 + threadIdx.x;  // 65536 = 2048*32
  int s = t >> 5, i = t & 31;
  float freq = powf(150000.0f, -(float)i * (1.0f / 32.0f));
  float ang = (float)pos[s] * freq;
  float sv, cv;
  sincosf(ang, &sv, &cv);
  tab[t] = make_float2(cv, sv);
}

// ---------------- f32 -> bf16 convert with K-pad: out [2048][2944] ----------------
__global__ __launch_bounds__(256) void k_convert_pad(const float* __restrict__ in,
                                                     u16* __restrict__ out) {
  int i = blockIdx.x * 256 + threadIdx.x;  // per 4 out elems; 2048*736 total
  int r = i / 736, c4 = i - r * 736;
  if (r >= 2048) return;
  ushort4 o = {0, 0, 0, 0};
  if (c4 < 720) {
    float4 v = *(const float4*)(in + (size_t)r * 2880 + c4 * 4);
    o.x = f2bf(v.x); o.y = f2bf(v.y); o.z = f2bf(v.z); o.w = f2bf(v.w);
  }
  ((ushort4*)out)[(size_t)r * 736 + c4] = o;
}

// ------ transpose+convert: in f32 [Kin][Nd] -> out bf16 [Npad][Kout], zero-padded ------
__global__ __launch_bounds__(256) void k_transpose(const float* __restrict__ in,
                                                   u16* __restrict__ out,
                                                   int Kin, int Kout, int Nd, int Npad) {
  __shared__ float tile[32][33];
  int n0 = blockIdx.x * 32, k0 = blockIdx.y * 32;
  int c = threadIdx.x & 31, r0 = threadIdx.x >> 5;
#pragma unroll
  for (int j = 0; j < 4; j++) {
    int r = r0 + j * 8;
    float v = 0.f;
    if (n0 + c < Nd && k0 + r < Kin) v = in[(size_t)(k0 + r) * Nd + n0 + c];
    tile[r][c] = v;
  }
  __syncthreads();
#pragma unroll
  for (int j = 0; j < 4; j++) {
    int rr = r0 + j * 8;  // local n
    int n = n0 + rr;
    if (n < Npad) out[(size_t)n * Kout + k0 + c] = f2bf(tile[c][rr]);
  }
}

// ======== GEMM1: 128x160 tiles, grid 512 (2 blocks/CU), BK=64, 4-phase schedule ======
// A [2048][2944] bf16, B [5120][2944] bf16 (B^T), out qkv bf16 [2048][5120], bias only.
// XCD swizzle: n-major slices (4 B-panels per XCD stay L2-resident).
__global__ __launch_bounds__(256, 2) void k_gemm1(const u16* __restrict__ Ag,
                                                  const u16* __restrict__ Bg,
                                                  const float* __restrict__ bias,
                                                  u16* __restrict__ C) {
  __shared__ u16 lds_[2][18432];
  u16* L = &lds_[0][0];
  const int tid = threadIdx.x;
  const int lane = tid & 63, wave = tid >> 6;
  const int wm = wave >> 1, wn = wave & 1;
  const int lr = lane & 15, lg = lane >> 4;
  const int bid = blockIdx.x;
  const int xcd = bid & 7, j = bid >> 3;       // 512 = 8 XCD x 64
  const int m0 = (j >> 2) * 128;               // 16 m-tiles
  const int n0 = (xcd * 4 + (j & 3)) * 160;    // 32 n-tiles, 4 per XCD

  f32x4 acc[4][5] = {};
  bf16x8 Bf[5], Af0, Af1;

  const int rb = (lg * 16) ^ (((lr >> 1) & 3) << 4);      // frag-read swizzled byte off
  const int arow = tid >> 2;                              // A staging row within 64-round
  const int axs = ((tid & 3) ^ ((tid >> 3) & 3)) << 3;    // A pre-swizzled chunk (elems)

  // B staging: 5 rounds per tile over linear [kh0 5120 | kh1 5120] region
  size_t boff[5];
#pragma unroll
  for (int r_ = 0; r_ < 5; r_++) {
    int e = r_ * 2048 + tid * 8;
    int bkh = (e >= 5120) ? 1 : 0;
    int re = e - bkh * 5120;
    int brow = re >> 5;
    int bch = (re >> 3) & 3;
    int bps = bch ^ ((brow >> 1) & 3);
    boff[r_] = (size_t)(n0 + brow) * KPAD + bkh * 32 + bps * 8;
  }

#define STA(b, kh, kt, r_)                                                      \
  gl_lds16(Ag + (size_t)(m0 + (r_) * 64 + arow) * KPAD + (kt) + (kh) * 32 + axs, \
           L + (b) * 18432 + (kh) * 4096 + (r_) * 2048 + wave * 512)
#define STB(b, kt, r_)                                                          \
  gl_lds16(Bg + boff[r_] + (kt), L + (b) * 18432 + 8192 + (r_) * 2048 + wave * 512)
#define RDB(b, kh)                                                              \
  { _Pragma("unroll") for (int nf = 0; nf < 5; nf++)                            \
      Bf[nf] = fragrd(L + (b) * 18432 + 8192 + (kh) * 5120,                     \
                      wn * 80 + nf * 16 + lr, rb); }
#define RDA(b, kh, mf0_)                                                        \
  { Af0 = fragrd(L + (b) * 18432 + (kh) * 4096, wm * 64 + (mf0_) * 16 + lr, rb); \
    Af1 = fragrd(L + (b) * 18432 + (kh) * 4096, wm * 64 + ((mf0_) + 1) * 16 + lr, rb); }
#define MM(ma, mb)                                                              \
  { __builtin_amdgcn_s_setprio(1);                                              \
    _Pragma("unroll") for (int nf = 0; nf < 5; nf++) {                          \
      acc[ma][nf] = MFMA16(Af0, Bf[nf], acc[ma][nf]);                           \
      acc[mb][nf] = MFMA16(Af1, Bf[nf], acc[mb][nf]); }                         \
    __builtin_amdgcn_s_setprio(0); }
#define BAR __builtin_amdgcn_s_barrier();
#define VM4 asm volatile("s_waitcnt vmcnt(4)" ::: "memory");
#define VM0 asm volatile("s_waitcnt vmcnt(0)" ::: "memory");

  // prologue: tile 0 -> buf0 (ops 1-9); certify ops 1-5 (A-kh0 + B r0..r2)
  STA(0, 0, 0, 0); STA(0, 0, 0, 1);
  STB(0, 0, 0); STB(0, 0, 1); STB(0, 0, 2); STB(0, 0, 3); STB(0, 0, 4);
  STA(0, 1, 0, 0); STA(0, 1, 0, 1);
  VM4 BAR

  for (int t = 0; t < 46; t++) {
    const int b = t & 1, nb = b ^ 1;
    const int kt1 = (t + 1) * 64;
    const bool st = (t < 45);
    RDB(b, 0) RDA(b, 0, 0)
    if (st) { STA(nb, 0, kt1, 0); STA(nb, 0, kt1, 1); STB(nb, kt1, 0); }
    BAR MM(0, 1) BAR
    RDA(b, 0, 2)
    if (st) { STB(nb, kt1, 1); STB(nb, kt1, 2); VM4 } else { VM0 }
    BAR MM(2, 3) BAR
    RDB(b, 1) RDA(b, 1, 0)
    if (st) { STB(nb, kt1, 3); STB(nb, kt1, 4); }
    BAR MM(0, 1) BAR
    RDA(b, 1, 2)
    if (st) { STA(nb, 1, kt1, 0); STA(nb, 1, kt1, 1); VM4 }
    BAR MM(2, 3) BAR
  }
#undef STA
#undef STB
#undef RDB
#undef RDA
#undef MM
#undef BAR
#undef VM4
#undef VM0

  // ---- epilogue: bias, bf16 store ----
#pragma unroll
  for (int mf = 0; mf < 4; mf++)
#pragma unroll
    for (int nf = 0; nf < 5; nf++) {
      int col = n0 + wn * 80 + nf * 16 + lr;
      float bv = bias[col];
#pragma unroll
      for (int rg = 0; rg < 4; rg++) {
        int row = m0 + wm * 64 + mf * 16 + lg * 4 + rg;
        C[(size_t)row * QKV_N + col] = f2bf(acc[mf][nf][rg] + bv);
      }
    }
}

// ======== GEMM2 (round-9 proven): 128x128, BK=64, 2-tile ring, counted vmcnt ========
// A = attn bf16 [2048][4096], B = woT bf16 [2944][4096], C f32 [2048][2880].
__global__ __launch_bounds__(256, 2) void k_gemm2(const u16* __restrict__ Ag,
                                                  const u16* __restrict__ Bg,
                                                  const float* __restrict__ bias,
                                                  float* __restrict__ C) {
  __shared__ u16 ldsbuf[2][16384];  // [buf][A 8192 | B 8192]
  const int tid = threadIdx.x;
  const int lane = tid & 63, wave = tid >> 6;
  const int wm = wave >> 1, wn = wave & 1;
  const int lr = lane & 15, lg = lane >> 4;
  int bid = blockIdx.x;
  int sb = (bid & 7) * 46 + (bid >> 3);  // 368 = 8 XCD x 46
  const int m0 = (sb / 23) * 128, n0 = (sb % 23) * 128;

  f32x4 acc[4][4] = {};

  const int srow = wave * 8 + (lane >> 3);         // within 32-row round
  const int sc = ((lane & 7) ^ (lane >> 3)) << 3;  // pre-swizzled chunk
  const u16* gA = Ag + (size_t)(m0 + srow) * ATTN_K + sc;
  const u16* gB = Bg + (size_t)(n0 + srow) * ATTN_K + sc;

#define G2_STAGE(kt, b)                                                          \
  {                                                                              \
    u16* Ab = &ldsbuf[b][0];                                                     \
    u16* Bb = &ldsbuf[b][8192];                                                  \
    _Pragma("unroll") for (int r = 0; r < 4; r++) {                              \
      gl_lds16(gA + (size_t)(r * 32) * ATTN_K + (kt), Ab + (r * 32 + wave * 8) * 64); \
      gl_lds16(gB + (size_t)(r * 32) * ATTN_K + (kt), Bb + (r * 32 + wave * 8) * 64); \
    }                                                                            \
  }

  G2_STAGE(0, 0)
  G2_STAGE(64, 1)
  asm volatile("s_waitcnt vmcnt(8)" ::: "memory");
  __builtin_amdgcn_s_barrier();

  for (int t = 0; t < 64; t++) {
    const int b = t & 1;
    const u16* La = &ldsbuf[b][0];
    const u16* Lb = &ldsbuf[b][8192];
    bf16x8 Bf[4][2];
#pragma unroll
    for (int nf = 0; nf < 4; nf++)
#pragma unroll
      for (int kh = 0; kh < 2; kh++)
        Bf[nf][kh] = lds_frag(Lb, wn * 64 + nf * 16 + lr, kh, lg);
    bf16x8 Af[2][2];
#pragma unroll
    for (int mi = 0; mi < 2; mi++)
#pragma unroll
      for (int kh = 0; kh < 2; kh++)
        Af[mi][kh] = lds_frag(La, wm * 64 + mi * 16 + lr, kh, lg);
#pragma unroll
    for (int q = 0; q < 2; q++) {
      bf16x8 An[2][2];
      if (q < 1) {
#pragma unroll
        for (int mi = 0; mi < 2; mi++)
#pragma unroll
          for (int kh = 0; kh < 2; kh++)
            An[mi][kh] = lds_frag(La, wm * 64 + ((q + 1) * 2 + mi) * 16 + lr, kh, lg);
      }
      __builtin_amdgcn_s_setprio(1);
#pragma unroll
      for (int mi = 0; mi < 2; mi++)
#pragma unroll
        for (int nf = 0; nf < 4; nf++)
#pragma unroll
          for (int kh = 0; kh < 2; kh++)
            acc[q * 2 + mi][nf] = MFMA16(Af[mi][kh], Bf[nf][kh], acc[q * 2 + mi][nf]);
      __builtin_amdgcn_s_setprio(0);
      if (q < 1) {
#pragma unroll
        for (int mi = 0; mi < 2; mi++)
#pragma unroll
          for (int kh = 0; kh < 2; kh++)
            Af[mi][kh] = An[mi][kh];
      }
    }
    __builtin_amdgcn_s_barrier();
    if (t <= 61) {
      G2_STAGE((t + 2) * 64, b)
      asm volatile("s_waitcnt vmcnt(8)" ::: "memory");
    } else {
      asm volatile("s_waitcnt vmcnt(0)" ::: "memory");
    }
    __builtin_amdgcn_s_barrier();
  }
#undef G2_STAGE

#pragma unroll
  for (int mi = 0; mi < 4; mi++)
#pragma unroll
    for (int ni = 0; ni < 4; ni++) {
      int row = m0 + wm * 64 + mi * 16 + lg * 4;
      int col = n0 + wn * 64 + ni * 16 + lr;
      if (col < 2880) {
        float bv = bias[col];
#pragma unroll
        for (int rg = 0; rg < 4; rg++)
          C[(size_t)(row + rg) * 2880 + col] = acc[mi][ni][rg] + bv;
      }
    }
}

// ---- attention QB=64: 1024 thr = 16 waves (8 heads x 2 query-halves); 192 keys staged
// once; each wave computes its 32 queries against its 160-key subwindow (offset qoff).
// RoPE fused on Q (in-reg) and K (staging).
__global__ __launch_bounds__(1024, 1) void k_attn(const u16* __restrict__ qkv,
                                                  const float* __restrict__ sinks,
                                                  const float2* __restrict__ tab,
                                                  u16* __restrict__ out) {
  __shared__ u16 Klds[192 * 64];      // XOR-swizzled rows
  __shared__ u16 Vt[64 * 200];        // V transposed [d][key], padded
  __shared__ u16 Pslab[16 * 32 * 40]; // per-wave P bounce
  const int hk = blockIdx.y;
  const int s0 = blockIdx.x * 64;
  const int kb = s0 - 127;
  const int tid = threadIdx.x;
  const int lane = tid & 63, w = tid >> 6;
  const int lr = lane & 15, lg = lane >> 4;
  const int head = hk * 8 + (w & 7);
  const int qoff = (w >> 3) * 32;

  // ---- stage K with fused RoPE: 192 keys x 4 chunk-pairs = 768 units ----
  if (tid < 768) {
    int key = tid >> 2, c = tid & 3;
    int kidx = kb + key;
    u16x8 v1 = {0, 0, 0, 0, 0, 0, 0, 0}, v2 = v1;
    if (kidx >= 0 && kidx < SEQ) {
      const u16* base = qkv + (size_t)kidx * QKV_N + 4096 + hk * 64;
      u16x8 x1 = *(const u16x8*)(base + c * 8);
      u16x8 x2 = *(const u16x8*)(base + 32 + c * 8);
      const float2* cs = tab + (size_t)kidx * 32 + c * 8;
#pragma unroll
      for (int j = 0; j < 8; j++) {
        float f1 = bf2f(x1[j]), f2 = bf2f(x2[j]);
        float2 t = cs[j];
        v1[j] = f2bf(f1 * t.x - f2 * t.y);
        v2[j] = f2bf(f2 * t.x + f1 * t.y);
      }
    }
    int o1 = (key * 128 + c * 16) ^ ((key & 7) << 4);
    int o2 = (key * 128 + (c + 4) * 16) ^ ((key & 7) << 4);
    *(u16x8*)((char*)Klds + o1) = v1;
    *(u16x8*)((char*)Klds + o2) = v2;
  }
  // ---- stage V (no rope): 192*16 units ----
  for (int e4 = tid; e4 < 192 * 16; e4 += 1024) {
    int key = e4 >> 4, d0 = (e4 & 15) * 4;
    int kidx = kb + key;
    ushort4 v = {0, 0, 0, 0};
    if (kidx >= 0 && kidx < SEQ)
      v = *(const ushort4*)(qkv + (size_t)kidx * QKV_N + 4608 + hk * 64 + d0);
    Vt[(d0 + 0) * 200 + key] = v.x;
    Vt[(d0 + 1) * 200 + key] = v.y;
    Vt[(d0 + 2) * 200 + key] = v.z;
    Vt[(d0 + 3) * 200 + key] = v.w;
  }

  // ---- Q frags with in-register RoPE ----
  bf16x8 qf[2][2];
#pragma unroll
  for (int rt = 0; rt < 2; rt++) {
    int s = s0 + qoff + rt * 16 + lr;
    const u16* base = qkv + (size_t)s * QKV_N + head * 64 + lg * 8;
    u16x8 r0 = *(const u16x8*)(base);
    u16x8 r1 = *(const u16x8*)(base + 32);
    const float2* cs = tab + (size_t)s * 32 + lg * 8;
    u16x8 y0, y1;
#pragma unroll
    for (int j = 0; j < 8; j++) {
      float f1 = bf2f(r0[j]), f2 = bf2f(r1[j]);
      float2 t = cs[j];
      y0[j] = f2bf(f1 * t.x - f2 * t.y);
      y1[j] = f2bf(f2 * t.x + f1 * t.y);
    }
    qf[rt][0] = __builtin_bit_cast(bf16x8, y0);
    qf[rt][1] = __builtin_bit_cast(bf16x8, y1);
  }
  __syncthreads();

  // ---- QK^T over this wave's 160-key subwindow ----
  f32x4 sc[2][10];
  f32x4 zz = {0.f, 0.f, 0.f, 0.f};
#pragma unroll
  for (int rt = 0; rt < 2; rt++)
#pragma unroll
    for (int nt = 0; nt < 10; nt++) sc[rt][nt] = zz;
#pragma unroll
  for (int nt = 0; nt < 10; nt++) {
    int key = qoff + nt * 16 + lr;   // absolute staged-key index
#pragma unroll
    for (int ks = 0; ks < 2; ks++) {
      int off = (key * 128 + ks * 64 + lg * 16) ^ ((key & 7) << 4);
      bf16x8 kf = *(const bf16x8*)((const char*)Klds + off);
      sc[0][nt] = MFMA16(qf[0][ks], kf, sc[0][nt]);
      sc[1][nt] = MFMA16(qf[1][ks], kf, sc[1][nt]);
    }
  }

  // ---- mask + scale (wave-local coords; same algebra as QB=32 version) ----
#pragma unroll
  for (int rt = 0; rt < 2; rt++)
#pragma unroll
    for (int nt = 0; nt < 10; nt++)
#pragma unroll
      for (int rg = 0; rg < 4; rg++) {
        int qq = rt * 16 + lg * 4 + rg;
        int jl = nt * 16 + lr;
        bool valid = (jl >= qq) && (jl <= qq + 127) && ((kb + qoff + jl) >= 0);
        sc[rt][nt][rg] = valid ? sc[rt][nt][rg] * SCALE : NEGINF;
      }

  const float sink = sinks[head];
  float den[2][4];
#pragma unroll
  for (int rt = 0; rt < 2; rt++)
#pragma unroll
    for (int rg = 0; rg < 4; rg++) {
      float m = NEGINF;
#pragma unroll
      for (int nt = 0; nt < 10; nt++) m = fmaxf(m, sc[rt][nt][rg]);
#pragma unroll
      for (int x = 1; x < 16; x <<= 1) m = fmaxf(m, __shfl_xor(m, x, 64));
      m = fmaxf(m, sink);
      float sum = 0.f;
#pragma unroll
      for (int nt = 0; nt < 10; nt++) {
        float p = __expf(sc[rt][nt][rg] - m);
        sc[rt][nt][rg] = p;
        sum += p;
      }
#pragma unroll
      for (int x = 1; x < 16; x <<= 1) sum += __shfl_xor(sum, x, 64);
      den[rt][rg] = sum + __expf(sink - m);
    }

  // ---- PV over the subwindow ----
  f32x4 oacc[2][4];
#pragma unroll
  for (int rt = 0; rt < 2; rt++)
#pragma unroll
    for (int dn = 0; dn < 4; dn++) oacc[rt][dn] = zz;
  u16* slab = &Pslab[w * 32 * 40];
#pragma unroll
  for (int kt = 0; kt < 5; kt++) {
#pragma unroll
    for (int rt = 0; rt < 2; rt++)
#pragma unroll
      for (int j2 = 0; j2 < 2; j2++)
#pragma unroll
        for (int rg = 0; rg < 4; rg++)
          slab[(rt * 16 + lg * 4 + rg) * 40 + j2 * 16 + lr] = f2bf(sc[rt][kt * 2 + j2][rg]);
    asm volatile("s_waitcnt lgkmcnt(0)" ::: "memory");
    __builtin_amdgcn_sched_barrier(0);
    bf16x8 pf0 = *(const bf16x8*)&slab[lr * 40 + lg * 8];
    bf16x8 pf1 = *(const bf16x8*)&slab[(16 + lr) * 40 + lg * 8];
#pragma unroll
    for (int dn = 0; dn < 4; dn++) {
      bf16x8 vf = *(const bf16x8*)&Vt[(dn * 16 + lr) * 200 + qoff + kt * 32 + lg * 8];
      oacc[0][dn] = MFMA16(pf0, vf, oacc[0][dn]);
      oacc[1][dn] = MFMA16(pf1, vf, oacc[1][dn]);
    }
  }

#pragma unroll
  for (int rt = 0; rt < 2; rt++)
#pragma unroll
    for (int dn = 0; dn < 4; dn++)
#pragma unroll
      for (int rg = 0; rg < 4; rg++) {
        int s = s0 + qoff + rt * 16 + lg * 4 + rg;
        float val = oacc[rt][dn][rg] / den[rt][rg];
        out[(size_t)s * ATTN_K + head * 64 + dn * 16 + lr] = f2bf(val);
      }
}

extern "C" void kernel_launch(void* const* d_in, const int* in_sizes, int n_in,
                              void* d_out, int out_size, void* d_ws, size_t ws_size,
                              hipStream_t stream) {
  const float* hs = (const float*)d_in[0];
  const int* pos = (const int*)d_in[1];
  const float* wqkv = (const float*)d_in[2];
  const float* bqkv = (const float*)d_in[3];
  const float* wo = (const float*)d_in[4];
  const float* bo = (const float*)d_in[5];
  const float* sinks = (const float*)d_in[6];
  float* out = (float*)d_out;

  char* ws = (char*)d_ws;
  u16* qkvb = (u16*)(ws + 0);               // 2048*5120*2 = 20,971,520 (bf16, un-roped)
  u16* hsb = (u16*)(ws + 41943040);         // 2048*2944*2 = 12,058,624
  u16* wqkvT = (u16*)(ws + 54001664);       // 5120*2944*2 = 30,146,560 -> ends 84,148,224
  u16* attnb = (u16*)(ws + 41943040);       // 2048*4096*2 (aliases dead hsb/wqkvT)
  u16* woT = (u16*)(ws + 84148224);         // 2944*4096*2 = 24,117,248 -> ends 108,265,472
  float2* tab = (float2*)(ws + 108265472);  // 2048*32*8   = 524,288

  k_rope_table<<<256, 256, 0, stream>>>(pos, tab);
  k_convert_pad<<<5888, 256, 0, stream>>>(hs, hsb);
  k_transpose<<<dim3(160, 92), 256, 0, stream>>>(wqkv, wqkvT, 2880, KPAD, 5120, 5120);
  k_transpose<<<dim3(92, 128), 256, 0, stream>>>(wo, woT, 4096, 4096, 2880, 2944);
  k_gemm1<<<512, 256, 0, stream>>>(hsb, wqkvT, bqkv, qkvb);
  k_attn<<<dim3(32, 8), 1024, 0, stream>>>(qkvb, sinks, tab, attnb);
  k_gemm2<<<368, 256, 0, stream>>>(attnb, woT, bo, out);
}

// Round 12
// 199.127 us; speedup vs baseline: 1.0532x; 1.0190x over previous
//
#include <hip/hip_runtime.h>

typedef unsigned short u16;
typedef __bf16 bf16x8 __attribute__((ext_vector_type(8)));
typedef float f32x4 __attribute__((ext_vector_type(4)));
typedef unsigned short u16x8 __attribute__((ext_vector_type(8)));

#define QKV_N 5120
#define SEQ 2048
#define ATTN_K 4096
#define KPAD 2944   // 2880 padded to 46*64
#define SCALE 0.125f
#define NEGINF -1e30f

__device__ __forceinline__ u16 f2bf(float f) {
  unsigned int u = __builtin_bit_cast(unsigned int, f);
  u = (u + 0x7FFFu + ((u >> 16) & 1u)) >> 16;
  return (u16)u;
}
__device__ __forceinline__ float bf2f(u16 u) {
  unsigned int x = ((unsigned int)u) << 16;
  return __builtin_bit_cast(float, x);
}

#define MFMA16(a, b, c) __builtin_amdgcn_mfma_f32_16x16x32_bf16((a), (b), (c), 0, 0, 0)

// async global->LDS, 16B per lane; LDS dest = wave-uniform base + lane*16
__device__ __forceinline__ void gl_lds16(const u16* g, u16* l) {
  __builtin_amdgcn_global_load_lds(
      (const __attribute__((address_space(1))) unsigned int*)(const void*)g,
      (__attribute__((address_space(3))) unsigned int*)(void*)l, 16, 0, 0);
}

// fragment read from [rows][32k] half-tile (64B rows); swizzle key (row>>1)&3
__device__ __forceinline__ bf16x8 fragrd(const u16* base, int row, int rb) {
  return *(const bf16x8*)((const char*)(base + row * 32) + rb);
}

// legacy frag read for GEMM2's [rows][64k] swizzled tile (128B rows)
__device__ __forceinline__ bf16x8 lds_frag(const u16* mat, int row, int kh, int lg) {
  int off = row * 128 + ((kh * 64 + lg * 16) ^ ((row & 7) << 4));
  return *(const bf16x8*)((const char*)mat + off);
}

// ---------------- RoPE table: tab[s*32+i] = {cos, sin} ----------------
__global__ __launch_bounds__(256) void k_rope_table(const int* __restrict__ pos,
                                                    float2* __restrict__ tab) {
  int t = blockIdx.x * 256 + threadIdx.x;  // 65536 = 2048*32
  int s = t >> 5, i = t & 31;
  float freq = powf(150000.0f, -(float)i * (1.0f / 32.0f));
  float ang = (float)pos[s] * freq;
  float sv, cv;
  sincosf(ang, &sv, &cv);
  tab[t] = make_float2(cv, sv);
}

// ---------------- f32 -> bf16 convert with K-pad: out [2048][2944] ----------------
__global__ __launch_bounds__(256) void k_convert_pad(const float* __restrict__ in,
                                                     u16* __restrict__ out) {
  int i = blockIdx.x * 256 + threadIdx.x;  // per 4 out elems; 2048*736 total
  int r = i / 736, c4 = i - r * 736;
  if (r >= 2048) return;
  ushort4 o = {0, 0, 0, 0};
  if (c4 < 720) {
    float4 v = *(const float4*)(in + (size_t)r * 2880 + c4 * 4);
    o.x = f2bf(v.x); o.y = f2bf(v.y); o.z = f2bf(v.z); o.w = f2bf(v.w);
  }
  ((ushort4*)out)[(size_t)r * 736 + c4] = o;
}

// ------ transpose+convert: in f32 [Kin][Nd] -> out bf16 [Npad][Kout], zero-padded ------
__global__ __launch_bounds__(256) void k_transpose(const float* __restrict__ in,
                                                   u16* __restrict__ out,
                                                   int Kin, int Kout, int Nd, int Npad) {
  __shared__ float tile[32][33];
  int n0 = blockIdx.x * 32, k0 = blockIdx.y * 32;
  int c = threadIdx.x & 31, r0 = threadIdx.x >> 5;
#pragma unroll
  for (int j = 0; j < 4; j++) {
    int r = r0 + j * 8;
    float v = 0.f;
    if (n0 + c < Nd && k0 + r < Kin) v = in[(size_t)(k0 + r) * Nd + n0 + c];
    tile[r][c] = v;
  }
  __syncthreads();
#pragma unroll
  for (int j = 0; j < 4; j++) {
    int rr = r0 + j * 8;  // local n
    int n = n0 + rr;
    if (n < Npad) out[(size_t)n * Kout + k0 + c] = f2bf(tile[c][rr]);
  }
}

// ======== GEMM1: 128x160 tiles, grid 512 (2 blocks/CU), BK=64, 4-phase schedule ======
// A [2048][2944] bf16, B [5120][2944] bf16 (B^T), out qkv bf16 [2048][5120], bias only.
// XCD swizzle: n-major slices (4 B-panels per XCD stay L2-resident).
__global__ __launch_bounds__(256, 2) void k_gemm1(const u16* __restrict__ Ag,
                                                  const u16* __restrict__ Bg,
                                                  const float* __restrict__ bias,
                                                  u16* __restrict__ C) {
  __shared__ u16 lds_[2][18432];
  u16* L = &lds_[0][0];
  const int tid = threadIdx.x;
  const int lane = tid & 63, wave = tid >> 6;
  const int wm = wave >> 1, wn = wave & 1;
  const int lr = lane & 15, lg = lane >> 4;
  const int bid = blockIdx.x;
  const int xcd = bid & 7, j = bid >> 3;       // 512 = 8 XCD x 64
  const int m0 = (j >> 2) * 128;               // 16 m-tiles
  const int n0 = (xcd * 4 + (j & 3)) * 160;    // 32 n-tiles, 4 per XCD

  f32x4 acc[4][5] = {};
  bf16x8 Bf[5], Af0, Af1;

  const int rb = (lg * 16) ^ (((lr >> 1) & 3) << 4);      // frag-read swizzled byte off
  const int arow = tid >> 2;                              // A staging row within 64-round
  const int axs = ((tid & 3) ^ ((tid >> 3) & 3)) << 3;    // A pre-swizzled chunk (elems)

  // B staging: 5 rounds per tile over linear [kh0 5120 | kh1 5120] region
  size_t boff[5];
#pragma unroll
  for (int r_ = 0; r_ < 5; r_++) {
    int e = r_ * 2048 + tid * 8;
    int bkh = (e >= 5120) ? 1 : 0;
    int re = e - bkh * 5120;
    int brow = re >> 5;
    int bch = (re >> 3) & 3;
    int bps = bch ^ ((brow >> 1) & 3);
    boff[r_] = (size_t)(n0 + brow) * KPAD + bkh * 32 + bps * 8;
  }

#define STA(b, kh, kt, r_)                                                      \
  gl_lds16(Ag + (size_t)(m0 + (r_) * 64 + arow) * KPAD + (kt) + (kh) * 32 + axs, \
           L + (b) * 18432 + (kh) * 4096 + (r_) * 2048 + wave * 512)
#define STB(b, kt, r_)                                                          \
  gl_lds16(Bg + boff[r_] + (kt), L + (b) * 18432 + 8192 + (r_) * 2048 + wave * 512)
#define RDB(b, kh)                                                              \
  { _Pragma("unroll") for (int nf = 0; nf < 5; nf++)                            \
      Bf[nf] = fragrd(L + (b) * 18432 + 8192 + (kh) * 5120,                     \
                      wn * 80 + nf * 16 + lr, rb); }
#define RDA(b, kh, mf0_)                                                        \
  { Af0 = fragrd(L + (b) * 18432 + (kh) * 4096, wm * 64 + (mf0_) * 16 + lr, rb); \
    Af1 = fragrd(L + (b) * 18432 + (kh) * 4096, wm * 64 + ((mf0_) + 1) * 16 + lr, rb); }
#define MM(ma, mb)                                                              \
  { __builtin_amdgcn_s_setprio(1);                                              \
    _Pragma("unroll") for (int nf = 0; nf < 5; nf++) {                          \
      acc[ma][nf] = MFMA16(Af0, Bf[nf], acc[ma][nf]);                           \
      acc[mb][nf] = MFMA16(Af1, Bf[nf], acc[mb][nf]); }                         \
    __builtin_amdgcn_s_setprio(0); }
#define BAR __builtin_amdgcn_s_barrier();
#define VM4 asm volatile("s_waitcnt vmcnt(4)" ::: "memory");
#define VM0 asm volatile("s_waitcnt vmcnt(0)" ::: "memory");

  // prologue: tile 0 -> buf0 (ops 1-9); certify ops 1-5 (A-kh0 + B r0..r2)
  STA(0, 0, 0, 0); STA(0, 0, 0, 1);
  STB(0, 0, 0); STB(0, 0, 1); STB(0, 0, 2); STB(0, 0, 3); STB(0, 0, 4);
  STA(0, 1, 0, 0); STA(0, 1, 0, 1);
  VM4 BAR

  for (int t = 0; t < 46; t++) {
    const int b = t & 1, nb = b ^ 1;
    const int kt1 = (t + 1) * 64;
    const bool st = (t < 45);
    RDB(b, 0) RDA(b, 0, 0)
    if (st) { STA(nb, 0, kt1, 0); STA(nb, 0, kt1, 1); STB(nb, kt1, 0); }
    BAR MM(0, 1) BAR
    RDA(b, 0, 2)
    if (st) { STB(nb, kt1, 1); STB(nb, kt1, 2); VM4 } else { VM0 }
    BAR MM(2, 3) BAR
    RDB(b, 1) RDA(b, 1, 0)
    if (st) { STB(nb, kt1, 3); STB(nb, kt1, 4); }
    BAR MM(0, 1) BAR
    RDA(b, 1, 2)
    if (st) { STA(nb, 1, kt1, 0); STA(nb, 1, kt1, 1); VM4 }
    BAR MM(2, 3) BAR
  }
#undef STA
#undef STB
#undef RDB
#undef RDA
#undef MM
#undef BAR
#undef VM4
#undef VM0

  // ---- epilogue: bias, bf16 store ----
#pragma unroll
  for (int mf = 0; mf < 4; mf++)
#pragma unroll
    for (int nf = 0; nf < 5; nf++) {
      int col = n0 + wn * 80 + nf * 16 + lr;
      float bv = bias[col];
#pragma unroll
      for (int rg = 0; rg < 4; rg++) {
        int row = m0 + wm * 64 + mf * 16 + lg * 4 + rg;
        C[(size_t)row * QKV_N + col] = f2bf(acc[mf][nf][rg] + bv);
      }
    }
}

// ======== GEMM2: 128x128, BK=64, 2-tile ring, counted vmcnt; n-major XCD swizzle ======
// A = attn bf16 [2048][4096], B = woT bf16 [2944][4096], C f32 [2048][2880].
__global__ __launch_bounds__(256, 2) void k_gemm2(const u16* __restrict__ Ag,
                                                  const u16* __restrict__ Bg,
                                                  const float* __restrict__ bias,
                                                  float* __restrict__ C) {
  __shared__ u16 ldsbuf[2][16384];  // [buf][A 8192 | B 8192]
  const int tid = threadIdx.x;
  const int lane = tid & 63, wave = tid >> 6;
  const int wm = wave >> 1, wn = wave & 1;
  const int lr = lane & 15, lg = lane >> 4;
  int bid = blockIdx.x;
  // n-major: XCD x gets linear ids [x*46,(x+1)*46) over l = n*16 + m
  int l = (bid & 7) * 46 + (bid >> 3);  // 368 = 8 XCD x 46
  const int m0 = (l & 15) * 128, n0 = (l >> 4) * 128;

  f32x4 acc[4][4] = {};

  const int srow = wave * 8 + (lane >> 3);         // within 32-row round
  const int sc = ((lane & 7) ^ (lane >> 3)) << 3;  // pre-swizzled chunk
  const u16* gA = Ag + (size_t)(m0 + srow) * ATTN_K + sc;
  const u16* gB = Bg + (size_t)(n0 + srow) * ATTN_K + sc;

#define G2_STAGE(kt, b)                                                          \
  {                                                                              \
    u16* Ab = &ldsbuf[b][0];                                                     \
    u16* Bb = &ldsbuf[b][8192];                                                  \
    _Pragma("unroll") for (int r = 0; r < 4; r++) {                              \
      gl_lds16(gA + (size_t)(r * 32) * ATTN_K + (kt), Ab + (r * 32 + wave * 8) * 64); \
      gl_lds16(gB + (size_t)(r * 32) * ATTN_K + (kt), Bb + (r * 32 + wave * 8) * 64); \
    }                                                                            \
  }

  G2_STAGE(0, 0)
  G2_STAGE(64, 1)
  asm volatile("s_waitcnt vmcnt(8)" ::: "memory");
  __builtin_amdgcn_s_barrier();

  for (int t = 0; t < 64; t++) {
    const int b = t & 1;
    const u16* La = &ldsbuf[b][0];
    const u16* Lb = &ldsbuf[b][8192];
    bf16x8 Bf[4][2];
#pragma unroll
    for (int nf = 0; nf < 4; nf++)
#pragma unroll
      for (int kh = 0; kh < 2; kh++)
        Bf[nf][kh] = lds_frag(Lb, wn * 64 + nf * 16 + lr, kh, lg);
    bf16x8 Af[2][2];
#pragma unroll
    for (int mi = 0; mi < 2; mi++)
#pragma unroll
      for (int kh = 0; kh < 2; kh++)
        Af[mi][kh] = lds_frag(La, wm * 64 + mi * 16 + lr, kh, lg);
#pragma unroll
    for (int q = 0; q < 2; q++) {
      bf16x8 An[2][2];
      if (q < 1) {
#pragma unroll
        for (int mi = 0; mi < 2; mi++)
#pragma unroll
          for (int kh = 0; kh < 2; kh++)
            An[mi][kh] = lds_frag(La, wm * 64 + ((q + 1) * 2 + mi) * 16 + lr, kh, lg);
      }
      __builtin_amdgcn_s_setprio(1);
#pragma unroll
      for (int mi = 0; mi < 2; mi++)
#pragma unroll
        for (int nf = 0; nf < 4; nf++)
#pragma unroll
          for (int kh = 0; kh < 2; kh++)
            acc[q * 2 + mi][nf] = MFMA16(Af[mi][kh], Bf[nf][kh], acc[q * 2 + mi][nf]);
      __builtin_amdgcn_s_setprio(0);
      if (q < 1) {
#pragma unroll
        for (int mi = 0; mi < 2; mi++)
#pragma unroll
          for (int kh = 0; kh < 2; kh++)
            Af[mi][kh] = An[mi][kh];
      }
    }
    __builtin_amdgcn_s_barrier();
    if (t <= 61) {
      G2_STAGE((t + 2) * 64, b)
      asm volatile("s_waitcnt vmcnt(8)" ::: "memory");
    } else {
      asm volatile("s_waitcnt vmcnt(0)" ::: "memory");
    }
    __builtin_amdgcn_s_barrier();
  }
#undef G2_STAGE

#pragma unroll
  for (int mi = 0; mi < 4; mi++)
#pragma unroll
    for (int ni = 0; ni < 4; ni++) {
      int row = m0 + wm * 64 + mi * 16 + lg * 4;
      int col = n0 + wn * 64 + ni * 16 + lr;
      if (col < 2880) {
        float bv = bias[col];
#pragma unroll
        for (int rg = 0; rg < 4; rg++)
          C[(size_t)(row + rg) * 2880 + col] = acc[mi][ni][rg] + bv;
      }
    }
}

// -------- sliding-window attention (QB=32, proven): RoPE fused on Q (in-reg) and K ----
__global__ __launch_bounds__(512, 2) void k_attn(const u16* __restrict__ qkv,
                                                 const float* __restrict__ sinks,
                                                 const float2* __restrict__ tab,
                                                 u16* __restrict__ out) {
  __shared__ u16 Klds[160 * 64];
  __shared__ u16 Vt[64 * 168];
  __shared__ u16 Pslab[8 * 32 * 40];
  const int hk = blockIdx.y;
  const int s0 = blockIdx.x * 32;
  const int kb = s0 - 127;
  const int tid = threadIdx.x;
  const int lane = tid & 63, w = tid >> 6;
  const int lr = lane & 15, lg = lane >> 4;

  for (int u = tid; u < 160 * 4; u += 512) {
    int key = u >> 2, c = u & 3;
    int kidx = kb + key;
    u16x8 v1 = {0, 0, 0, 0, 0, 0, 0, 0}, v2 = v1;
    if (kidx >= 0 && kidx < SEQ) {
      const u16* base = qkv + (size_t)kidx * QKV_N + 4096 + hk * 64;
      u16x8 x1 = *(const u16x8*)(base + c * 8);
      u16x8 x2 = *(const u16x8*)(base + 32 + c * 8);
      const float2* cs = tab + (size_t)kidx * 32 + c * 8;
#pragma unroll
      for (int j = 0; j < 8; j++) {
        float f1 = bf2f(x1[j]), f2 = bf2f(x2[j]);
        float2 t = cs[j];
        v1[j] = f2bf(f1 * t.x - f2 * t.y);
        v2[j] = f2bf(f2 * t.x + f1 * t.y);
      }
    }
    int o1 = (key * 128 + c * 16) ^ ((key & 7) << 4);
    int o2 = (key * 128 + (c + 4) * 16) ^ ((key & 7) << 4);
    *(u16x8*)((char*)Klds + o1) = v1;
    *(u16x8*)((char*)Klds + o2) = v2;
  }
  for (int e4 = tid; e4 < 160 * 16; e4 += 512) {
    int key = e4 >> 4, d0 = (e4 & 15) * 4;
    int kidx = kb + key;
    ushort4 v = {0, 0, 0, 0};
    if (kidx >= 0 && kidx < SEQ)
      v = *(const ushort4*)(qkv + (size_t)kidx * QKV_N + 4608 + hk * 64 + d0);
    Vt[(d0 + 0) * 168 + key] = v.x;
    Vt[(d0 + 1) * 168 + key] = v.y;
    Vt[(d0 + 2) * 168 + key] = v.z;
    Vt[(d0 + 3) * 168 + key] = v.w;
  }

  const int head = hk * 8 + w;
  bf16x8 qf[2][2];
#pragma unroll
  for (int rt = 0; rt < 2; rt++) {
    int s = s0 + rt * 16 + lr;
    const u16* base = qkv + (size_t)s * QKV_N + head * 64 + lg * 8;
    u16x8 r0 = *(const u16x8*)(base);
    u16x8 r1 = *(const u16x8*)(base + 32);
    const float2* cs = tab + (size_t)s * 32 + lg * 8;
    u16x8 y0, y1;
#pragma unroll
    for (int j = 0; j < 8; j++) {
      float f1 = bf2f(r0[j]), f2 = bf2f(r1[j]);
      float2 t = cs[j];
      y0[j] = f2bf(f1 * t.x - f2 * t.y);
      y1[j] = f2bf(f2 * t.x + f1 * t.y);
    }
    qf[rt][0] = __builtin_bit_cast(bf16x8, y0);
    qf[rt][1] = __builtin_bit_cast(bf16x8, y1);
  }
  __syncthreads();

  f32x4 sc[2][10];
  f32x4 zz = {0.f, 0.f, 0.f, 0.f};
#pragma unroll
  for (int rt = 0; rt < 2; rt++)
#pragma unroll
    for (int nt = 0; nt < 10; nt++) sc[rt][nt] = zz;
#pragma unroll
  for (int nt = 0; nt < 10; nt++) {
    int key = nt * 16 + lr;
#pragma unroll
    for (int ks = 0; ks < 2; ks++) {
      int off = (key * 128 + ks * 64 + lg * 16) ^ ((key & 7) << 4);
      bf16x8 kf = *(const bf16x8*)((const char*)Klds + off);
      sc[0][nt] = MFMA16(qf[0][ks], kf, sc[0][nt]);
      sc[1][nt] = MFMA16(qf[1][ks], kf, sc[1][nt]);
    }
  }

#pragma unroll
  for (int rt = 0; rt < 2; rt++)
#pragma unroll
    for (int nt = 0; nt < 10; nt++)
#pragma unroll
      for (int rg = 0; rg < 4; rg++) {
        int qq = rt * 16 + lg * 4 + rg;
        int j = nt * 16 + lr;
        bool valid = (j >= qq) && (j <= qq + 127) && ((kb + j) >= 0);
        sc[rt][nt][rg] = valid ? sc[rt][nt][rg] * SCALE : NEGINF;
      }

  const float sink = sinks[head];
  float den[2][4];
#pragma unroll
  for (int rt = 0; rt < 2; rt++)
#pragma unroll
    for (int rg = 0; rg < 4; rg++) {
      float m = NEGINF;
#pragma unroll
      for (int nt = 0; nt < 10; nt++) m = fmaxf(m, sc[rt][nt][rg]);
#pragma unroll
      for (int x = 1; x < 16; x <<= 1) m = fmaxf(m, __shfl_xor(m, x, 64));
      m = fmaxf(m, sink);
      float sum = 0.f;
#pragma unroll
      for (int nt = 0; nt < 10; nt++) {
        float p = __expf(sc[rt][nt][rg] - m);
        sc[rt][nt][rg] = p;
        sum += p;
      }
#pragma unroll
      for (int x = 1; x < 16; x <<= 1) sum += __shfl_xor(sum, x, 64);
      den[rt][rg] = sum + __expf(sink - m);
    }

  f32x4 oacc[2][4];
#pragma unroll
  for (int rt = 0; rt < 2; rt++)
#pragma unroll
    for (int dn = 0; dn < 4; dn++) oacc[rt][dn] = zz;
  u16* slab = &Pslab[w * 32 * 40];
#pragma unroll
  for (int kt = 0; kt < 5; kt++) {
#pragma unroll
    for (int rt = 0; rt < 2; rt++)
#pragma unroll
      for (int j2 = 0; j2 < 2; j2++)
#pragma unroll
        for (int rg = 0; rg < 4; rg++)
          slab[(rt * 16 + lg * 4 + rg) * 40 + j2 * 16 + lr] = f2bf(sc[rt][kt * 2 + j2][rg]);
    asm volatile("s_waitcnt lgkmcnt(0)" ::: "memory");
    __builtin_amdgcn_sched_barrier(0);
    bf16x8 pf0 = *(const bf16x8*)&slab[lr * 40 + lg * 8];
    bf16x8 pf1 = *(const bf16x8*)&slab[(16 + lr) * 40 + lg * 8];
#pragma unroll
    for (int dn = 0; dn < 4; dn++) {
      bf16x8 vf = *(const bf16x8*)&Vt[(dn * 16 + lr) * 168 + kt * 32 + lg * 8];
      oacc[0][dn] = MFMA16(pf0, vf, oacc[0][dn]);
      oacc[1][dn] = MFMA16(pf1, vf, oacc[1][dn]);
    }
  }

#pragma unroll
  for (int rt = 0; rt < 2; rt++)
#pragma unroll
    for (int dn = 0; dn < 4; dn++)
#pragma unroll
      for (int rg = 0; rg < 4; rg++) {
        int s = s0 + rt * 16 + lg * 4 + rg;
        float val = oacc[rt][dn][rg] / den[rt][rg];
        out[(size_t)s * ATTN_K + head * 64 + dn * 16 + lr] = f2bf(val);
      }
}

extern "C" void kernel_launch(void* const* d_in, const int* in_sizes, int n_in,
                              void* d_out, int out_size, void* d_ws, size_t ws_size,
                              hipStream_t stream) {
  const float* hs = (const float*)d_in[0];
  const int* pos = (const int*)d_in[1];
  const float* wqkv = (const float*)d_in[2];
  const float* bqkv = (const float*)d_in[3];
  const float* wo = (const float*)d_in[4];
  const float* bo = (const float*)d_in[5];
  const float* sinks = (const float*)d_in[6];
  float* out = (float*)d_out;

  char* ws = (char*)d_ws;
  u16* qkvb = (u16*)(ws + 0);               // 2048*5120*2 = 20,971,520 (bf16, un-roped)
  u16* hsb = (u16*)(ws + 41943040);         // 2048*2944*2 = 12,058,624
  u16* wqkvT = (u16*)(ws + 54001664);       // 5120*2944*2 = 30,146,560 -> ends 84,148,224
  u16* attnb = (u16*)(ws + 41943040);       // 2048*4096*2 (aliases dead hsb/wqkvT)
  u16* woT = (u16*)(ws + 84148224);         // 2944*4096*2 = 24,117,248 -> ends 108,265,472
  float2* tab = (float2*)(ws + 108265472);  // 2048*32*8   = 524,288

  k_rope_table<<<256, 256, 0, stream>>>(pos, tab);
  k_convert_pad<<<5888, 256, 0, stream>>>(hs, hsb);
  k_transpose<<<dim3(160, 92), 256, 0, stream>>>(wqkv, wqkvT, 2880, KPAD, 5120, 5120);
  k_transpose<<<dim3(92, 128), 256, 0, stream>>>(wo, woT, 4096, 4096, 2880, 2944);
  k_gemm1<<<512, 256, 0, stream>>>(hsb, wqkvT, bqkv, qkvb);
  k_attn<<<dim3(64, 8), 512, 0, stream>>>(qkvb, sinks, tab, attnb);
  k_gemm2<<<368, 256, 0, stream>>>(attnb, woT, bo, out);
}

// Round 13
// 190.801 us; speedup vs baseline: 1.0991x; 1.0436x over previous
//
#include <hip/hip_runtime.h>

typedef unsigned short u16;
typedef __bf16 bf16x8 __attribute__((ext_vector_type(8)));
typedef float f32x4 __attribute__((ext_vector_type(4)));
typedef unsigned short u16x8 __attribute__((ext_vector_type(8)));

#define QKV_N 5120
#define SEQ 2048
#define ATTN_K 4096
#define KPAD 2944   // 2880 padded to 46*64
#define SCALE 0.125f
#define NEGINF -1e30f

__device__ __forceinline__ u16 f2bf(float f) {
  unsigned int u = __builtin_bit_cast(unsigned int, f);
  u = (u + 0x7FFFu + ((u >> 16) & 1u)) >> 16;
  return (u16)u;
}
__device__ __forceinline__ float bf2f(u16 u) {
  unsigned int x = ((unsigned int)u) << 16;
  return __builtin_bit_cast(float, x);
}

#define MFMA16(a, b, c) __builtin_amdgcn_mfma_f32_16x16x32_bf16((a), (b), (c), 0, 0, 0)

// async global->LDS, 16B per lane; LDS dest = wave-uniform base + lane*16
__device__ __forceinline__ void gl_lds16(const u16* g, u16* l) {
  __builtin_amdgcn_global_load_lds(
      (const __attribute__((address_space(1))) unsigned int*)(const void*)g,
      (__attribute__((address_space(3))) unsigned int*)(void*)l, 16, 0, 0);
}

// fragment read from [rows][32k] half-tile (64B rows); swizzle key (row>>1)&3
__device__ __forceinline__ bf16x8 fragrd(const u16* base, int row, int rb) {
  return *(const bf16x8*)((const char*)(base + row * 32) + rb);
}

// legacy frag read for GEMM2's [rows][64k] swizzled tile (128B rows)
__device__ __forceinline__ bf16x8 lds_frag(const u16* mat, int row, int kh, int lg) {
  int off = row * 128 + ((kh * 64 + lg * 16) ^ ((row & 7) << 4));
  return *(const bf16x8*)((const char*)mat + off);
}

// ---------------- RoPE table: tab[s*32+i] = {cos, sin} ----------------
__global__ __launch_bounds__(256) void k_rope_table(const int* __restrict__ pos,
                                                    float2* __restrict__ tab) {
  int t = blockIdx.x * 256 + threadIdx.x;  // 65536 = 2048*32
  int s = t >> 5, i = t & 31;
  float freq = powf(150000.0f, -(float)i * (1.0f / 32.0f));
  float ang = (float)pos[s] * freq;
  float sv, cv;
  sincosf(ang, &sv, &cv);
  tab[t] = make_float2(cv, sv);
}

// ---------------- f32 -> bf16 convert with K-pad: out [2048][2944] ----------------
__global__ __launch_bounds__(256) void k_convert_pad(const float* __restrict__ in,
                                                     u16* __restrict__ out) {
  int i = blockIdx.x * 256 + threadIdx.x;  // per 4 out elems; 2048*736 total
  int r = i / 736, c4 = i - r * 736;
  if (r >= 2048) return;
  ushort4 o = {0, 0, 0, 0};
  if (c4 < 720) {
    float4 v = *(const float4*)(in + (size_t)r * 2880 + c4 * 4);
    o.x = f2bf(v.x); o.y = f2bf(v.y); o.z = f2bf(v.z); o.w = f2bf(v.w);
  }
  ((ushort4*)out)[(size_t)r * 736 + c4] = o;
}

// ------ transpose+convert: in f32 [Kin][Nd] -> out bf16 [Npad][Kout], zero-padded ------
__global__ __launch_bounds__(256) void k_transpose(const float* __restrict__ in,
                                                   u16* __restrict__ out,
                                                   int Kin, int Kout, int Nd, int Npad) {
  __shared__ float tile[32][33];
  int n0 = blockIdx.x * 32, k0 = blockIdx.y * 32;
  int c = threadIdx.x & 31, r0 = threadIdx.x >> 5;
#pragma unroll
  for (int j = 0; j < 4; j++) {
    int r = r0 + j * 8;
    float v = 0.f;
    if (n0 + c < Nd && k0 + r < Kin) v = in[(size_t)(k0 + r) * Nd + n0 + c];
    tile[r][c] = v;
  }
  __syncthreads();
#pragma unroll
  for (int j = 0; j < 4; j++) {
    int rr = r0 + j * 8;  // local n
    int n = n0 + rr;
    if (n < Npad) out[(size_t)n * Kout + k0 + c] = f2bf(tile[c][rr]);
  }
}

// ======== GEMM1: 128x160 tiles, grid 512 (2 blocks/CU), BK=64, 2-phase schedule ======
// A [2048][2944] bf16, B [5120][2944] bf16 (B^T), out qkv bf16 [2048][5120], bias only.
// 2 phases/tile (one per kh), 20 MFMA/phase, 4 barriers/tile.
// Stage plan: p0 issues next ops1-5 {A0,A1,B0,B1,B2} then vmcnt(5);
//             p1 issues ops6-9 {B3,B4,A2,A3} then vmcnt(4).
// Invariant entering each tile: exactly ops6-9 (4) in flight.
__global__ __launch_bounds__(256, 2) void k_gemm1(const u16* __restrict__ Ag,
                                                  const u16* __restrict__ Bg,
                                                  const float* __restrict__ bias,
                                                  u16* __restrict__ C) {
  __shared__ u16 lds_[2][18432];
  u16* L = &lds_[0][0];
  const int tid = threadIdx.x;
  const int lane = tid & 63, wave = tid >> 6;
  const int wm = wave >> 1, wn = wave & 1;
  const int lr = lane & 15, lg = lane >> 4;
  const int bid = blockIdx.x;
  const int xcd = bid & 7, j = bid >> 3;       // 512 = 8 XCD x 64
  const int m0 = (j >> 2) * 128;               // 16 m-tiles
  const int n0 = (xcd * 4 + (j & 3)) * 160;    // 32 n-tiles, 4 per XCD

  f32x4 acc[4][5] = {};
  bf16x8 Bf[5], Af0, Af1, Af2, Af3;

  const int rb = (lg * 16) ^ (((lr >> 1) & 3) << 4);      // frag-read swizzled byte off
  const int arow = tid >> 2;                              // A staging row within 64-round
  const int axs = ((tid & 3) ^ ((tid >> 3) & 3)) << 3;    // A pre-swizzled chunk (elems)

  // B staging: 5 rounds per tile over linear [kh0 5120 | kh1 5120] region
  size_t boff[5];
#pragma unroll
  for (int r_ = 0; r_ < 5; r_++) {
    int e = r_ * 2048 + tid * 8;
    int bkh = (e >= 5120) ? 1 : 0;
    int re = e - bkh * 5120;
    int brow = re >> 5;
    int bch = (re >> 3) & 3;
    int bps = bch ^ ((brow >> 1) & 3);
    boff[r_] = (size_t)(n0 + brow) * KPAD + bkh * 32 + bps * 8;
  }

#define STA(b, kh, kt, r_)                                                      \
  gl_lds16(Ag + (size_t)(m0 + (r_) * 64 + arow) * KPAD + (kt) + (kh) * 32 + axs, \
           L + (b) * 18432 + (kh) * 4096 + (r_) * 2048 + wave * 512)
#define STB(b, kt, r_)                                                          \
  gl_lds16(Bg + boff[r_] + (kt), L + (b) * 18432 + 8192 + (r_) * 2048 + wave * 512)
#define RDB(b, kh)                                                              \
  { _Pragma("unroll") for (int nf = 0; nf < 5; nf++)                            \
      Bf[nf] = fragrd(L + (b) * 18432 + 8192 + (kh) * 5120,                     \
                      wn * 80 + nf * 16 + lr, rb); }
#define RDA4(b, kh)                                                             \
  { Af0 = fragrd(L + (b) * 18432 + (kh) * 4096, wm * 64 + 0 * 16 + lr, rb);     \
    Af1 = fragrd(L + (b) * 18432 + (kh) * 4096, wm * 64 + 1 * 16 + lr, rb);     \
    Af2 = fragrd(L + (b) * 18432 + (kh) * 4096, wm * 64 + 2 * 16 + lr, rb);     \
    Af3 = fragrd(L + (b) * 18432 + (kh) * 4096, wm * 64 + 3 * 16 + lr, rb); }
#define MM20                                                                    \
  { __builtin_amdgcn_s_setprio(1);                                              \
    _Pragma("unroll") for (int nf = 0; nf < 5; nf++) {                          \
      acc[0][nf] = MFMA16(Af0, Bf[nf], acc[0][nf]);                             \
      acc[1][nf] = MFMA16(Af1, Bf[nf], acc[1][nf]);                             \
      acc[2][nf] = MFMA16(Af2, Bf[nf], acc[2][nf]);                             \
      acc[3][nf] = MFMA16(Af3, Bf[nf], acc[3][nf]); }                           \
    __builtin_amdgcn_s_setprio(0); }
#define BAR __builtin_amdgcn_s_barrier();
#define VM5 asm volatile("s_waitcnt vmcnt(5)" ::: "memory");
#define VM4 asm volatile("s_waitcnt vmcnt(4)" ::: "memory");
#define VM0 asm volatile("s_waitcnt vmcnt(0)" ::: "memory");

  // prologue: tile 0 -> buf0 (ops 1-9); certify ops 1-5 (A-kh0 + B r0..r2)
  STA(0, 0, 0, 0); STA(0, 0, 0, 1);
  STB(0, 0, 0); STB(0, 0, 1); STB(0, 0, 2); STB(0, 0, 3); STB(0, 0, 4);
  STA(0, 1, 0, 0); STA(0, 1, 0, 1);
  VM4 BAR

  for (int t = 0; t < 46; t++) {
    const int b = t & 1, nb = b ^ 1;
    const int kt1 = (t + 1) * 64;
    const bool st = (t < 45);
    // p0 (kh0): 9 frag reads; stage next ops1-5; certify cur ops6-9 for p1
    RDB(b, 0) RDA4(b, 0)
    if (st) {
      STA(nb, 0, kt1, 0); STA(nb, 0, kt1, 1);
      STB(nb, kt1, 0); STB(nb, kt1, 1); STB(nb, kt1, 2);
      VM5
    } else {
      VM0
    }
    BAR MM20 BAR
    // p1 (kh1): 9 frag reads; stage next ops6-9; certify next ops1-5
    RDB(b, 1) RDA4(b, 1)
    if (st) {
      STB(nb, kt1, 3); STB(nb, kt1, 4);
      STA(nb, 1, kt1, 0); STA(nb, 1, kt1, 1);
      VM4
    }
    BAR MM20 BAR
  }
#undef STA
#undef STB
#undef RDB
#undef RDA4
#undef MM20
#undef VM5
#undef VM4
#undef VM0

  // ---- epilogue: bias, bf16 store ----
#pragma unroll
  for (int mf = 0; mf < 4; mf++)
#pragma unroll
    for (int nf = 0; nf < 5; nf++) {
      int col = n0 + wn * 80 + nf * 16 + lr;
      float bv = bias[col];
#pragma unroll
      for (int rg = 0; rg < 4; rg++) {
        int row = m0 + wm * 64 + mf * 16 + lg * 4 + rg;
        C[(size_t)row * QKV_N + col] = f2bf(acc[mf][nf][rg] + bv);
      }
    }
}

// ======== GEMM2: 128x96 tiles, grid 480, 2-tile ring (r5 structure), counted vmcnt ====
// A = attn bf16 [2048][4096], B = woT bf16 [2944][4096], C f32 [2048][2880].
// 2880 = 30*96 exactly (no col guard). 7 stage-ops/tile; vmcnt(7). n-major XCD swizzle.
__global__ __launch_bounds__(256, 2) void k_gemm2(const u16* __restrict__ Ag,
                                                  const u16* __restrict__ Bg,
                                                  const float* __restrict__ bias,
                                                  float* __restrict__ C) {
  __shared__ u16 ldsbuf[2][14336];  // [buf][A 8192 | B 6144]
  const int tid = threadIdx.x;
  const int lane = tid & 63, wave = tid >> 6;
  const int wm = wave >> 1, wn = wave & 1;
  const int lr = lane & 15, lg = lane >> 4;
  int bid = blockIdx.x;
  // n-major: XCD x gets linear ids [x*60,(x+1)*60) over l = n*16 + m (480 = 8*60)
  int l = (bid & 7) * 60 + (bid >> 3);
  const int m0 = (l & 15) * 128, n0 = (l >> 4) * 96;

  f32x4 acc[4][3] = {};

  const int srow = wave * 8 + (lane >> 3);         // within 32-row round
  const int sc = ((lane & 7) ^ (lane >> 3)) << 3;  // pre-swizzled chunk
  const u16* gA = Ag + (size_t)(m0 + srow) * ATTN_K + sc;
  const u16* gB = Bg + (size_t)(n0 + srow) * ATTN_K + sc;

#define G2_STAGE(kt, b)                                                          \
  {                                                                              \
    u16* Ab = &ldsbuf[b][0];                                                     \
    u16* Bb = &ldsbuf[b][8192];                                                  \
    _Pragma("unroll") for (int r = 0; r < 4; r++)                                \
      gl_lds16(gA + (size_t)(r * 32) * ATTN_K + (kt), Ab + (r * 32 + wave * 8) * 64); \
    _Pragma("unroll") for (int r = 0; r < 3; r++)                                \
      gl_lds16(gB + (size_t)(r * 32) * ATTN_K + (kt), Bb + (r * 32 + wave * 8) * 64); \
  }

  G2_STAGE(0, 0)
  G2_STAGE(64, 1)
  asm volatile("s_waitcnt vmcnt(7)" ::: "memory");
  __builtin_amdgcn_s_barrier();

  for (int t = 0; t < 64; t++) {
    const int b = t & 1;
    const u16* La = &ldsbuf[b][0];
    const u16* Lb = &ldsbuf[b][8192];
    bf16x8 Bf[3][2];
#pragma unroll
    for (int nf = 0; nf < 3; nf++)
#pragma unroll
      for (int kh = 0; kh < 2; kh++)
        Bf[nf][kh] = lds_frag(Lb, wn * 48 + nf * 16 + lr, kh, lg);
    bf16x8 Af[2][2];
#pragma unroll
    for (int mi = 0; mi < 2; mi++)
#pragma unroll
      for (int kh = 0; kh < 2; kh++)
        Af[mi][kh] = lds_frag(La, wm * 64 + mi * 16 + lr, kh, lg);
#pragma unroll
    for (int q = 0; q < 2; q++) {
      bf16x8 An[2][2];
      if (q < 1) {
#pragma unroll
        for (int mi = 0; mi < 2; mi++)
#pragma unroll
          for (int kh = 0; kh < 2; kh++)
            An[mi][kh] = lds_frag(La, wm * 64 + ((q + 1) * 2 + mi) * 16 + lr, kh, lg);
      }
      __builtin_amdgcn_s_setprio(1);
#pragma unroll
      for (int mi = 0; mi < 2; mi++)
#pragma unroll
        for (int nf = 0; nf < 3; nf++)
#pragma unroll
          for (int kh = 0; kh < 2; kh++)
            acc[q * 2 + mi][nf] = MFMA16(Af[mi][kh], Bf[nf][kh], acc[q * 2 + mi][nf]);
      __builtin_amdgcn_s_setprio(0);
      if (q < 1) {
#pragma unroll
        for (int mi = 0; mi < 2; mi++)
#pragma unroll
          for (int kh = 0; kh < 2; kh++)
            Af[mi][kh] = An[mi][kh];
      }
    }
    __builtin_amdgcn_s_barrier();
    if (t <= 61) {
      G2_STAGE((t + 2) * 64, b)
      asm volatile("s_waitcnt vmcnt(7)" ::: "memory");
    } else {
      asm volatile("s_waitcnt vmcnt(0)" ::: "memory");
    }
    __builtin_amdgcn_s_barrier();
  }
#undef G2_STAGE

#pragma unroll
  for (int mi = 0; mi < 4; mi++)
#pragma unroll
    for (int ni = 0; ni < 3; ni++) {
      int row = m0 + wm * 64 + mi * 16 + lg * 4;
      int col = n0 + wn * 48 + ni * 16 + lr;
      float bv = bias[col];
#pragma unroll
      for (int rg = 0; rg < 4; rg++)
        C[(size_t)(row + rg) * 2880 + col] = acc[mi][ni][rg] + bv;
    }
}

// -------- sliding-window attention (QB=32, proven): RoPE fused on Q (in-reg) and K ----
__global__ __launch_bounds__(512, 2) void k_attn(const u16* __restrict__ qkv,
                                                 const float* __restrict__ sinks,
                                                 const float2* __restrict__ tab,
                                                 u16* __restrict__ out) {
  __shared__ u16 Klds[160 * 64];
  __shared__ u16 Vt[64 * 168];
  __shared__ u16 Pslab[8 * 32 * 40];
  const int hk = blockIdx.y;
  const int s0 = blockIdx.x * 32;
  const int kb = s0 - 127;
  const int tid = threadIdx.x;
  const int lane = tid & 63, w = tid >> 6;
  const int lr = lane & 15, lg = lane >> 4;

  for (int u = tid; u < 160 * 4; u += 512) {
    int key = u >> 2, c = u & 3;
    int kidx = kb + key;
    u16x8 v1 = {0, 0, 0, 0, 0, 0, 0, 0}, v2 = v1;
    if (kidx >= 0 && kidx < SEQ) {
      const u16* base = qkv + (size_t)kidx * QKV_N + 4096 + hk * 64;
      u16x8 x1 = *(const u16x8*)(base + c * 8);
      u16x8 x2 = *(const u16x8*)(base + 32 + c * 8);
      const float2* cs = tab + (size_t)kidx * 32 + c * 8;
#pragma unroll
      for (int j = 0; j < 8; j++) {
        float f1 = bf2f(x1[j]), f2 = bf2f(x2[j]);
        float2 t = cs[j];
        v1[j] = f2bf(f1 * t.x - f2 * t.y);
        v2[j] = f2bf(f2 * t.x + f1 * t.y);
      }
    }
    int o1 = (key * 128 + c * 16) ^ ((key & 7) << 4);
    int o2 = (key * 128 + (c + 4) * 16) ^ ((key & 7) << 4);
    *(u16x8*)((char*)Klds + o1) = v1;
    *(u16x8*)((char*)Klds + o2) = v2;
  }
  for (int e4 = tid; e4 < 160 * 16; e4 += 512) {
    int key = e4 >> 4, d0 = (e4 & 15) * 4;
    int kidx = kb + key;
    ushort4 v = {0, 0, 0, 0};
    if (kidx >= 0 && kidx < SEQ)
      v = *(const ushort4*)(qkv + (size_t)kidx * QKV_N + 4608 + hk * 64 + d0);
    Vt[(d0 + 0) * 168 + key] = v.x;
    Vt[(d0 + 1) * 168 + key] = v.y;
    Vt[(d0 + 2) * 168 + key] = v.z;
    Vt[(d0 + 3) * 168 + key] = v.w;
  }

  const int head = hk * 8 + w;
  bf16x8 qf[2][2];
#pragma unroll
  for (int rt = 0; rt < 2; rt++) {
    int s = s0 + rt * 16 + lr;
    const u16* base = qkv + (size_t)s * QKV_N + head * 64 + lg * 8;
    u16x8 r0 = *(const u16x8*)(base);
    u16x8 r1 = *(const u16x8*)(base + 32);
    const float2* cs = tab + (size_t)s * 32 + lg * 8;
    u16x8 y0, y1;
#pragma unroll
    for (int j = 0; j < 8; j++) {
      float f1 = bf2f(r0[j]), f2 = bf2f(r1[j]);
      float2 t = cs[j];
      y0[j] = f2bf(f1 * t.x - f2 * t.y);
      y1[j] = f2bf(f2 * t.x + f1 * t.y);
    }
    qf[rt][0] = __builtin_bit_cast(bf16x8, y0);
    qf[rt][1] = __builtin_bit_cast(bf16x8, y1);
  }
  __syncthreads();

  f32x4 sc[2][10];
  f32x4 zz = {0.f, 0.f, 0.f, 0.f};
#pragma unroll
  for (int rt = 0; rt < 2; rt++)
#pragma unroll
    for (int nt = 0; nt < 10; nt++) sc[rt][nt] = zz;
#pragma unroll
  for (int nt = 0; nt < 10; nt++) {
    int key = nt * 16 + lr;
#pragma unroll
    for (int ks = 0; ks < 2; ks++) {
      int off = (key * 128 + ks * 64 + lg * 16) ^ ((key & 7) << 4);
      bf16x8 kf = *(const bf16x8*)((const char*)Klds + off);
      sc[0][nt] = MFMA16(qf[0][ks], kf, sc[0][nt]);
      sc[1][nt] = MFMA16(qf[1][ks], kf, sc[1][nt]);
    }
  }

#pragma unroll
  for (int rt = 0; rt < 2; rt++)
#pragma unroll
    for (int nt = 0; nt < 10; nt++)
#pragma unroll
      for (int rg = 0; rg < 4; rg++) {
        int qq = rt * 16 + lg * 4 + rg;
        int j = nt * 16 + lr;
        bool valid = (j >= qq) && (j <= qq + 127) && ((kb + j) >= 0);
        sc[rt][nt][rg] = valid ? sc[rt][nt][rg] * SCALE : NEGINF;
      }

  const float sink = sinks[head];
  float den[2][4];
#pragma unroll
  for (int rt = 0; rt < 2; rt++)
#pragma unroll
    for (int rg = 0; rg < 4; rg++) {
      float m = NEGINF;
#pragma unroll
      for (int nt = 0; nt < 10; nt++) m = fmaxf(m, sc[rt][nt][rg]);
#pragma unroll
      for (int x = 1; x < 16; x <<= 1) m = fmaxf(m, __shfl_xor(m, x, 64));
      m = fmaxf(m, sink);
      float sum = 0.f;
#pragma unroll
      for (int nt = 0; nt < 10; nt++) {
        float p = __expf(sc[rt][nt][rg] - m);
        sc[rt][nt][rg] = p;
        sum += p;
      }
#pragma unroll
      for (int x = 1; x < 16; x <<= 1) sum += __shfl_xor(sum, x, 64);
      den[rt][rg] = sum + __expf(sink - m);
    }

  f32x4 oacc[2][4];
#pragma unroll
  for (int rt = 0; rt < 2; rt++)
#pragma unroll
    for (int dn = 0; dn < 4; dn++) oacc[rt][dn] = zz;
  u16* slab = &Pslab[w * 32 * 40];
#pragma unroll
  for (int kt = 0; kt < 5; kt++) {
#pragma unroll
    for (int rt = 0; rt < 2; rt++)
#pragma unroll
      for (int j2 = 0; j2 < 2; j2++)
#pragma unroll
        for (int rg = 0; rg < 4; rg++)
          slab[(rt * 16 + lg * 4 + rg) * 40 + j2 * 16 + lr] = f2bf(sc[rt][kt * 2 + j2][rg]);
    asm volatile("s_waitcnt lgkmcnt(0)" ::: "memory");
    __builtin_amdgcn_sched_barrier(0);
    bf16x8 pf0 = *(const bf16x8*)&slab[lr * 40 + lg * 8];
    bf16x8 pf1 = *(const bf16x8*)&slab[(16 + lr) * 40 + lg * 8];
#pragma unroll
    for (int dn = 0; dn < 4; dn++) {
      bf16x8 vf = *(const bf16x8*)&Vt[(dn * 16 + lr) * 168 + kt * 32 + lg * 8];
      oacc[0][dn] = MFMA16(pf0, vf, oacc[0][dn]);
      oacc[1][dn] = MFMA16(pf1, vf, oacc[1][dn]);
    }
  }

#pragma unroll
  for (int rt = 0; rt < 2; rt++)
#pragma unroll
    for (int dn = 0; dn < 4; dn++)
#pragma unroll
      for (int rg = 0; rg < 4; rg++) {
        int s = s0 + rt * 16 + lg * 4 + rg;
        float val = oacc[rt][dn][rg] / den[rt][rg];
        out[(size_t)s * ATTN_K + head * 64 + dn * 16 + lr] = f2bf(val);
      }
}

extern "C" void kernel_launch(void* const* d_in, const int* in_sizes, int n_in,
                              void* d_out, int out_size, void* d_ws, size_t ws_size,
                              hipStream_t stream) {
  const float* hs = (const float*)d_in[0];
  const int* pos = (const int*)d_in[1];
  const float* wqkv = (const float*)d_in[2];
  const float* bqkv = (const float*)d_in[3];
  const float* wo = (const float*)d_in[4];
  const float* bo = (const float*)d_in[5];
  const float* sinks = (const float*)d_in[6];
  float* out = (float*)d_out;

  char* ws = (char*)d_ws;
  u16* qkvb = (u16*)(ws + 0);               // 2048*5120*2 = 20,971,520 (bf16, un-roped)
  u16* hsb = (u16*)(ws + 41943040);         // 2048*2944*2 = 12,058,624
  u16* wqkvT = (u16*)(ws + 54001664);       // 5120*2944*2 = 30,146,560 -> ends 84,148,224
  u16* attnb = (u16*)(ws + 41943040);       // 2048*4096*2 (aliases dead hsb/wqkvT)
  u16* woT = (u16*)(ws + 84148224);         // 2944*4096*2 = 24,117,248 -> ends 108,265,472
  float2* tab = (float2*)(ws + 108265472);  // 2048*32*8   = 524,288

  k_rope_table<<<256, 256, 0, stream>>>(pos, tab);
  k_convert_pad<<<5888, 256, 0, stream>>>(hs, hsb);
  k_transpose<<<dim3(160, 92), 256, 0, stream>>>(wqkv, wqkvT, 2880, KPAD, 5120, 5120);
  k_transpose<<<dim3(92, 128), 256, 0, stream>>>(wo, woT, 4096, 4096, 2880, 2944);
  k_gemm1<<<512, 256, 0, stream>>>(hsb, wqkvT, bqkv, qkvb);
  k_attn<<<dim3(64, 8), 512, 0, stream>>>(qkvb, sinks, tab, attnb);
  k_gemm2<<<480, 256, 0, stream>>>(attnb, woT, bo, out);
}

// Round 14
// 179.823 us; speedup vs baseline: 1.1662x; 1.0610x over previous
//
#include <hip/hip_runtime.h>

typedef unsigned short u16;
typedef __bf16 bf16x8 __attribute__((ext_vector_type(8)));
typedef float f32x4 __attribute__((ext_vector_type(4)));
typedef unsigned short u16x8 __attribute__((ext_vector_type(8)));

#define QKV_N 5120
#define SEQ 2048
#define ATTN_K 4096
#define KPAD 2944   // 2880 padded to 46*64
#define SCALE 0.125f
#define NEGINF -1e30f

__device__ __forceinline__ u16 f2bf(float f) {
  unsigned int u = __builtin_bit_cast(unsigned int, f);
  u = (u + 0x7FFFu + ((u >> 16) & 1u)) >> 16;
  return (u16)u;
}
__device__ __forceinline__ float bf2f(u16 u) {
  unsigned int x = ((unsigned int)u) << 16;
  return __builtin_bit_cast(float, x);
}

#define MFMA16(a, b, c) __builtin_amdgcn_mfma_f32_16x16x32_bf16((a), (b), (c), 0, 0, 0)

// async global->LDS, 16B per lane; LDS dest = wave-uniform base + lane*16
__device__ __forceinline__ void gl_lds16(const u16* g, u16* l) {
  __builtin_amdgcn_global_load_lds(
      (const __attribute__((address_space(1))) unsigned int*)(const void*)g,
      (__attribute__((address_space(3))) unsigned int*)(void*)l, 16, 0, 0);
}

// fragment read from [rows][32k] half-tile (64B rows); swizzle key (row>>1)&3
__device__ __forceinline__ bf16x8 fragrd(const u16* base, int row, int rb) {
  return *(const bf16x8*)((const char*)(base + row * 32) + rb);
}

// legacy frag read for GEMM2's [rows][64k] swizzled tile (128B rows)
__device__ __forceinline__ bf16x8 lds_frag(const u16* mat, int row, int kh, int lg) {
  int off = row * 128 + ((kh * 64 + lg * 16) ^ ((row & 7) << 4));
  return *(const bf16x8*)((const char*)mat + off);
}

// ========== merged prep: rope table | convert+pad | transpose wqkv | transpose wo ======
// blocks [0,256): rope table; [256,6144): hs f32->bf16 pad; [6144,20864): wqkvT;
// [20864,32640): woT. Branch is block-uniform.
__global__ __launch_bounds__(256) void k_prep(const int* __restrict__ pos,
                                              float2* __restrict__ tab,
                                              const float* __restrict__ hs,
                                              u16* __restrict__ hsb,
                                              const float* __restrict__ wqkv,
                                              u16* __restrict__ wqkvT,
                                              const float* __restrict__ wo,
                                              u16* __restrict__ woT) {
  __shared__ float tile[32][33];
  const int blk = blockIdx.x;
  if (blk < 256) {
    int t = blk * 256 + threadIdx.x;  // 65536 = 2048*32
    int s = t >> 5, i = t & 31;
    float freq = powf(150000.0f, -(float)i * (1.0f / 32.0f));
    float ang = (float)pos[s] * freq;
    float sv, cv;
    sincosf(ang, &sv, &cv);
    tab[t] = make_float2(cv, sv);
  } else if (blk < 6144) {
    int i = (blk - 256) * 256 + threadIdx.x;  // 2048*736
    int r = i / 736, c4 = i - r * 736;
    if (r < 2048) {
      ushort4 o = {0, 0, 0, 0};
      if (c4 < 720) {
        float4 v = *(const float4*)(hs + (size_t)r * 2880 + c4 * 4);
        o.x = f2bf(v.x); o.y = f2bf(v.y); o.z = f2bf(v.z); o.w = f2bf(v.w);
      }
      ((ushort4*)hsb)[(size_t)r * 736 + c4] = o;
    }
  } else {
    const float* in;
    u16* out;
    int Kin, Kout, Nd, Npad, bx, by;
    if (blk < 20864) {
      int q = blk - 6144;  // 160 x 92
      bx = q % 160; by = q / 160;
      in = wqkv; out = wqkvT; Kin = 2880; Kout = KPAD; Nd = 5120; Npad = 5120;
    } else {
      int q = blk - 20864;  // 92 x 128
      bx = q % 92; by = q / 92;
      in = wo; out = woT; Kin = 4096; Kout = 4096; Nd = 2880; Npad = 2944;
    }
    int n0 = bx * 32, k0 = by * 32;
    int c = threadIdx.x & 31, r0 = threadIdx.x >> 5;
#pragma unroll
    for (int j = 0; j < 4; j++) {
      int r = r0 + j * 8;
      float v = 0.f;
      if (n0 + c < Nd && k0 + r < Kin) v = in[(size_t)(k0 + r) * Nd + n0 + c];
      tile[r][c] = v;
    }
    __syncthreads();
#pragma unroll
    for (int j = 0; j < 4; j++) {
      int rr = r0 + j * 8;
      int n = n0 + rr;
      if (n < Npad) out[(size_t)n * Kout + k0 + c] = f2bf(tile[c][rr]);
    }
  }
}

// ======== GEMM1 (round-12 proven): 128x160, grid 512, BK=64, 4-phase schedule ======
// A [2048][2944] bf16, B [5120][2944] bf16 (B^T), out qkv bf16 [2048][5120], bias only.
// XCD swizzle: n-major slices (4 B-panels per XCD stay L2-resident).
__global__ __launch_bounds__(256, 2) void k_gemm1(const u16* __restrict__ Ag,
                                                  const u16* __restrict__ Bg,
                                                  const float* __restrict__ bias,
                                                  u16* __restrict__ C) {
  __shared__ u16 lds_[2][18432];
  u16* L = &lds_[0][0];
  const int tid = threadIdx.x;
  const int lane = tid & 63, wave = tid >> 6;
  const int wm = wave >> 1, wn = wave & 1;
  const int lr = lane & 15, lg = lane >> 4;
  const int bid = blockIdx.x;
  const int xcd = bid & 7, j = bid >> 3;       // 512 = 8 XCD x 64
  const int m0 = (j >> 2) * 128;               // 16 m-tiles
  const int n0 = (xcd * 4 + (j & 3)) * 160;    // 32 n-tiles, 4 per XCD

  f32x4 acc[4][5] = {};
  bf16x8 Bf[5], Af0, Af1;

  const int rb = (lg * 16) ^ (((lr >> 1) & 3) << 4);      // frag-read swizzled byte off
  const int arow = tid >> 2;                              // A staging row within 64-round
  const int axs = ((tid & 3) ^ ((tid >> 3) & 3)) << 3;    // A pre-swizzled chunk (elems)

  // B staging: 5 rounds per tile over linear [kh0 5120 | kh1 5120] region
  size_t boff[5];
#pragma unroll
  for (int r_ = 0; r_ < 5; r_++) {
    int e = r_ * 2048 + tid * 8;
    int bkh = (e >= 5120) ? 1 : 0;
    int re = e - bkh * 5120;
    int brow = re >> 5;
    int bch = (re >> 3) & 3;
    int bps = bch ^ ((brow >> 1) & 3);
    boff[r_] = (size_t)(n0 + brow) * KPAD + bkh * 32 + bps * 8;
  }

#define STA(b, kh, kt, r_)                                                      \
  gl_lds16(Ag + (size_t)(m0 + (r_) * 64 + arow) * KPAD + (kt) + (kh) * 32 + axs, \
           L + (b) * 18432 + (kh) * 4096 + (r_) * 2048 + wave * 512)
#define STB(b, kt, r_)                                                          \
  gl_lds16(Bg + boff[r_] + (kt), L + (b) * 18432 + 8192 + (r_) * 2048 + wave * 512)
#define RDB(b, kh)                                                              \
  { _Pragma("unroll") for (int nf = 0; nf < 5; nf++)                            \
      Bf[nf] = fragrd(L + (b) * 18432 + 8192 + (kh) * 5120,                     \
                      wn * 80 + nf * 16 + lr, rb); }
#define RDA(b, kh, mf0_)                                                        \
  { Af0 = fragrd(L + (b) * 18432 + (kh) * 4096, wm * 64 + (mf0_) * 16 + lr, rb); \
    Af1 = fragrd(L + (b) * 18432 + (kh) * 4096, wm * 64 + ((mf0_) + 1) * 16 + lr, rb); }
#define MM(ma, mb)                                                              \
  { __builtin_amdgcn_s_setprio(1);                                              \
    _Pragma("unroll") for (int nf = 0; nf < 5; nf++) {                          \
      acc[ma][nf] = MFMA16(Af0, Bf[nf], acc[ma][nf]);                           \
      acc[mb][nf] = MFMA16(Af1, Bf[nf], acc[mb][nf]); }                         \
    __builtin_amdgcn_s_setprio(0); }
#define BAR __builtin_amdgcn_s_barrier();
#define VM4 asm volatile("s_waitcnt vmcnt(4)" ::: "memory");
#define VM0 asm volatile("s_waitcnt vmcnt(0)" ::: "memory");

  // prologue: tile 0 -> buf0 (ops 1-9); certify ops 1-5 (A-kh0 + B r0..r2)
  STA(0, 0, 0, 0); STA(0, 0, 0, 1);
  STB(0, 0, 0); STB(0, 0, 1); STB(0, 0, 2); STB(0, 0, 3); STB(0, 0, 4);
  STA(0, 1, 0, 0); STA(0, 1, 0, 1);
  VM4 BAR

  for (int t = 0; t < 46; t++) {
    const int b = t & 1, nb = b ^ 1;
    const int kt1 = (t + 1) * 64;
    const bool st = (t < 45);
    RDB(b, 0) RDA(b, 0, 0)
    if (st) { STA(nb, 0, kt1, 0); STA(nb, 0, kt1, 1); STB(nb, kt1, 0); }
    BAR MM(0, 1) BAR
    RDA(b, 0, 2)
    if (st) { STB(nb, kt1, 1); STB(nb, kt1, 2); VM4 } else { VM0 }
    BAR MM(2, 3) BAR
    RDB(b, 1) RDA(b, 1, 0)
    if (st) { STB(nb, kt1, 3); STB(nb, kt1, 4); }
    BAR MM(0, 1) BAR
    RDA(b, 1, 2)
    if (st) { STA(nb, 1, kt1, 0); STA(nb, 1, kt1, 1); VM4 }
    BAR MM(2, 3) BAR
  }
#undef STA
#undef STB
#undef RDB
#undef RDA
#undef MM
#undef VM4
#undef VM0

  // ---- epilogue: bias, bf16 store ----
#pragma unroll
  for (int mf = 0; mf < 4; mf++)
#pragma unroll
    for (int nf = 0; nf < 5; nf++) {
      int col = n0 + wn * 80 + nf * 16 + lr;
      float bv = bias[col];
#pragma unroll
      for (int rg = 0; rg < 4; rg++) {
        int row = m0 + wm * 64 + mf * 16 + lg * 4 + rg;
        C[(size_t)row * QKV_N + col] = f2bf(acc[mf][nf][rg] + bv);
      }
    }
}

// ======== GEMM2 (round-13 proven): 128x96, grid 480, 2-tile ring, counted vmcnt ====
// A = attn bf16 [2048][4096], B = woT bf16 [2944][4096], C f32 [2048][2880].
__global__ __launch_bounds__(256, 2) void k_gemm2(const u16* __restrict__ Ag,
                                                  const u16* __restrict__ Bg,
                                                  const float* __restrict__ bias,
                                                  float* __restrict__ C) {
  __shared__ u16 ldsbuf[2][14336];  // [buf][A 8192 | B 6144]
  const int tid = threadIdx.x;
  const int lane = tid & 63, wave = tid >> 6;
  const int wm = wave >> 1, wn = wave & 1;
  const int lr = lane & 15, lg = lane >> 4;
  int bid = blockIdx.x;
  int l = (bid & 7) * 60 + (bid >> 3);  // 480 = 8 XCD x 60, n-major
  const int m0 = (l & 15) * 128, n0 = (l >> 4) * 96;

  f32x4 acc[4][3] = {};

  const int srow = wave * 8 + (lane >> 3);         // within 32-row round
  const int sc = ((lane & 7) ^ (lane >> 3)) << 3;  // pre-swizzled chunk
  const u16* gA = Ag + (size_t)(m0 + srow) * ATTN_K + sc;
  const u16* gB = Bg + (size_t)(n0 + srow) * ATTN_K + sc;

#define G2_STAGE(kt, b)                                                          \
  {                                                                              \
    u16* Ab = &ldsbuf[b][0];                                                     \
    u16* Bb = &ldsbuf[b][8192];                                                  \
    _Pragma("unroll") for (int r = 0; r < 4; r++)                                \
      gl_lds16(gA + (size_t)(r * 32) * ATTN_K + (kt), Ab + (r * 32 + wave * 8) * 64); \
    _Pragma("unroll") for (int r = 0; r < 3; r++)                                \
      gl_lds16(gB + (size_t)(r * 32) * ATTN_K + (kt), Bb + (r * 32 + wave * 8) * 64); \
  }

  G2_STAGE(0, 0)
  G2_STAGE(64, 1)
  asm volatile("s_waitcnt vmcnt(7)" ::: "memory");
  __builtin_amdgcn_s_barrier();

  for (int t = 0; t < 64; t++) {
    const int b = t & 1;
    const u16* La = &ldsbuf[b][0];
    const u16* Lb = &ldsbuf[b][8192];
    bf16x8 Bf[3][2];
#pragma unroll
    for (int nf = 0; nf < 3; nf++)
#pragma unroll
      for (int kh = 0; kh < 2; kh++)
        Bf[nf][kh] = lds_frag(Lb, wn * 48 + nf * 16 + lr, kh, lg);
    bf16x8 Af[2][2];
#pragma unroll
    for (int mi = 0; mi < 2; mi++)
#pragma unroll
      for (int kh = 0; kh < 2; kh++)
        Af[mi][kh] = lds_frag(La, wm * 64 + mi * 16 + lr, kh, lg);
#pragma unroll
    for (int q = 0; q < 2; q++) {
      bf16x8 An[2][2];
      if (q < 1) {
#pragma unroll
        for (int mi = 0; mi < 2; mi++)
#pragma unroll
          for (int kh = 0; kh < 2; kh++)
            An[mi][kh] = lds_frag(La, wm * 64 + ((q + 1) * 2 + mi) * 16 + lr, kh, lg);
      }
      __builtin_amdgcn_s_setprio(1);
#pragma unroll
      for (int mi = 0; mi < 2; mi++)
#pragma unroll
        for (int nf = 0; nf < 3; nf++)
#pragma unroll
          for (int kh = 0; kh < 2; kh++)
            acc[q * 2 + mi][nf] = MFMA16(Af[mi][kh], Bf[nf][kh], acc[q * 2 + mi][nf]);
      __builtin_amdgcn_s_setprio(0);
      if (q < 1) {
#pragma unroll
        for (int mi = 0; mi < 2; mi++)
#pragma unroll
          for (int kh = 0; kh < 2; kh++)
            Af[mi][kh] = An[mi][kh];
      }
    }
    __builtin_amdgcn_s_barrier();
    if (t <= 61) {
      G2_STAGE((t + 2) * 64, b)
      asm volatile("s_waitcnt vmcnt(7)" ::: "memory");
    } else {
      asm volatile("s_waitcnt vmcnt(0)" ::: "memory");
    }
    __builtin_amdgcn_s_barrier();
  }
#undef G2_STAGE

#pragma unroll
  for (int mi = 0; mi < 4; mi++)
#pragma unroll
    for (int ni = 0; ni < 3; ni++) {
      int row = m0 + wm * 64 + mi * 16 + lg * 4;
      int col = n0 + wn * 48 + ni * 16 + lr;
      float bv = bias[col];
#pragma unroll
      for (int rg = 0; rg < 4; rg++)
        C[(size_t)(row + rg) * 2880 + col] = acc[mi][ni][rg] + bv;
    }
}

// ---- attention QB=64 @ 512 thr: stage 192 keys once; each of 8 waves processes its
// head's TWO 32-query subtiles sequentially (key-window offset qs*32). RoPE fused.
__global__ __launch_bounds__(512, 2) void k_attn(const u16* __restrict__ qkv,
                                                 const float* __restrict__ sinks,
                                                 const float2* __restrict__ tab,
                                                 u16* __restrict__ out) {
  __shared__ u16 Klds[192 * 64];      // XOR-swizzled rows (24.0 KB)
  __shared__ u16 Vt[64 * 200];        // V transposed [d][key], padded (25.0 KB)
  __shared__ u16 Pslab[8 * 32 * 40];  // per-wave P bounce (20.0 KB)
  const int hk = blockIdx.y;
  const int s0 = blockIdx.x * 64;
  const int kb = s0 - 127;
  const int tid = threadIdx.x;
  const int lane = tid & 63, w = tid >> 6;
  const int lr = lane & 15, lg = lane >> 4;
  const int head = hk * 8 + w;

  // ---- stage K with fused RoPE: 192 keys x 4 chunk-pairs = 768 units ----
  for (int u = tid; u < 192 * 4; u += 512) {
    int key = u >> 2, c = u & 3;
    int kidx = kb + key;
    u16x8 v1 = {0, 0, 0, 0, 0, 0, 0, 0}, v2 = v1;
    if (kidx >= 0 && kidx < SEQ) {
      const u16* base = qkv + (size_t)kidx * QKV_N + 4096 + hk * 64;
      u16x8 x1 = *(const u16x8*)(base + c * 8);
      u16x8 x2 = *(const u16x8*)(base + 32 + c * 8);
      const float2* cs = tab + (size_t)kidx * 32 + c * 8;
#pragma unroll
      for (int jj = 0; jj < 8; jj++) {
        float f1 = bf2f(x1[jj]), f2 = bf2f(x2[jj]);
        float2 t = cs[jj];
        v1[jj] = f2bf(f1 * t.x - f2 * t.y);
        v2[jj] = f2bf(f2 * t.x + f1 * t.y);
      }
    }
    int o1 = (key * 128 + c * 16) ^ ((key & 7) << 4);
    int o2 = (key * 128 + (c + 4) * 16) ^ ((key & 7) << 4);
    *(u16x8*)((char*)Klds + o1) = v1;
    *(u16x8*)((char*)Klds + o2) = v2;
  }
  // ---- stage V (no rope): 192*16 units ----
  for (int e4 = tid; e4 < 192 * 16; e4 += 512) {
    int key = e4 >> 4, d0 = (e4 & 15) * 4;
    int kidx = kb + key;
    ushort4 v = {0, 0, 0, 0};
    if (kidx >= 0 && kidx < SEQ)
      v = *(const ushort4*)(qkv + (size_t)kidx * QKV_N + 4608 + hk * 64 + d0);
    Vt[(d0 + 0) * 200 + key] = v.x;
    Vt[(d0 + 1) * 200 + key] = v.y;
    Vt[(d0 + 2) * 200 + key] = v.z;
    Vt[(d0 + 3) * 200 + key] = v.w;
  }
  __syncthreads();

  const float sink = sinks[head];
  u16* slab = &Pslab[w * 32 * 40];
  f32x4 zz = {0.f, 0.f, 0.f, 0.f};

  for (int qs = 0; qs < 2; qs++) {
    const int qbase = s0 + qs * 32;   // query rows
    const int koff = qs * 32;         // staged-key window offset

    // ---- Q frags with in-register RoPE ----
    bf16x8 qf[2][2];
#pragma unroll
    for (int rt = 0; rt < 2; rt++) {
      int s = qbase + rt * 16 + lr;
      const u16* base = qkv + (size_t)s * QKV_N + head * 64 + lg * 8;
      u16x8 r0 = *(const u16x8*)(base);
      u16x8 r1 = *(const u16x8*)(base + 32);
      const float2* cs = tab + (size_t)s * 32 + lg * 8;
      u16x8 y0, y1;
#pragma unroll
      for (int jj = 0; jj < 8; jj++) {
        float f1 = bf2f(r0[jj]), f2 = bf2f(r1[jj]);
        float2 t = cs[jj];
        y0[jj] = f2bf(f1 * t.x - f2 * t.y);
        y1[jj] = f2bf(f2 * t.x + f1 * t.y);
      }
      qf[rt][0] = __builtin_bit_cast(bf16x8, y0);
      qf[rt][1] = __builtin_bit_cast(bf16x8, y1);
    }

    // ---- QK^T over this subtile's 160-key window ----
    f32x4 sc[2][10];
#pragma unroll
    for (int rt = 0; rt < 2; rt++)
#pragma unroll
      for (int nt = 0; nt < 10; nt++) sc[rt][nt] = zz;
#pragma unroll
    for (int nt = 0; nt < 10; nt++) {
      int key = koff + nt * 16 + lr;
#pragma unroll
      for (int ks = 0; ks < 2; ks++) {
        int off = (key * 128 + ks * 64 + lg * 16) ^ ((key & 7) << 4);
        bf16x8 kf = *(const bf16x8*)((const char*)Klds + off);
        sc[0][nt] = MFMA16(qf[0][ks], kf, sc[0][nt]);
        sc[1][nt] = MFMA16(qf[1][ks], kf, sc[1][nt]);
      }
    }

    // ---- mask + scale (subtile-local coords) ----
#pragma unroll
    for (int rt = 0; rt < 2; rt++)
#pragma unroll
      for (int nt = 0; nt < 10; nt++)
#pragma unroll
        for (int rg = 0; rg < 4; rg++) {
          int qq = rt * 16 + lg * 4 + rg;
          int jl = nt * 16 + lr;
          bool valid = (jl >= qq) && (jl <= qq + 127) && ((kb + koff + jl) >= 0);
          sc[rt][nt][rg] = valid ? sc[rt][nt][rg] * SCALE : NEGINF;
        }

    // ---- softmax ----
    float den[2][4];
#pragma unroll
    for (int rt = 0; rt < 2; rt++)
#pragma unroll
      for (int rg = 0; rg < 4; rg++) {
        float m = NEGINF;
#pragma unroll
        for (int nt = 0; nt < 10; nt++) m = fmaxf(m, sc[rt][nt][rg]);
#pragma unroll
        for (int x = 1; x < 16; x <<= 1) m = fmaxf(m, __shfl_xor(m, x, 64));
        m = fmaxf(m, sink);
        float sum = 0.f;
#pragma unroll
        for (int nt = 0; nt < 10; nt++) {
          float p = __expf(sc[rt][nt][rg] - m);
          sc[rt][nt][rg] = p;
          sum += p;
        }
#pragma unroll
        for (int x = 1; x < 16; x <<= 1) sum += __shfl_xor(sum, x, 64);
        den[rt][rg] = sum + __expf(sink - m);
      }

    // ---- PV over the window ----
    f32x4 oacc[2][4];
#pragma unroll
    for (int rt = 0; rt < 2; rt++)
#pragma unroll
      for (int dn = 0; dn < 4; dn++) oacc[rt][dn] = zz;
#pragma unroll
    for (int kt = 0; kt < 5; kt++) {
#pragma unroll
      for (int rt = 0; rt < 2; rt++)
#pragma unroll
        for (int j2 = 0; j2 < 2; j2++)
#pragma unroll
          for (int rg = 0; rg < 4; rg++)
            slab[(rt * 16 + lg * 4 + rg) * 40 + j2 * 16 + lr] =
                f2bf(sc[rt][kt * 2 + j2][rg]);
      asm volatile("s_waitcnt lgkmcnt(0)" ::: "memory");
      __builtin_amdgcn_sched_barrier(0);
      bf16x8 pf0 = *(const bf16x8*)&slab[lr * 40 + lg * 8];
      bf16x8 pf1 = *(const bf16x8*)&slab[(16 + lr) * 40 + lg * 8];
#pragma unroll
      for (int dn = 0; dn < 4; dn++) {
        bf16x8 vf = *(const bf16x8*)&Vt[(dn * 16 + lr) * 200 + koff + kt * 32 + lg * 8];
        oacc[0][dn] = MFMA16(pf0, vf, oacc[0][dn]);
        oacc[1][dn] = MFMA16(pf1, vf, oacc[1][dn]);
      }
    }

    // ---- write normalized output (bf16 for GEMM2) ----
#pragma unroll
    for (int rt = 0; rt < 2; rt++)
#pragma unroll
      for (int dn = 0; dn < 4; dn++)
#pragma unroll
        for (int rg = 0; rg < 4; rg++) {
          int s = qbase + rt * 16 + lg * 4 + rg;
          float val = oacc[rt][dn][rg] / den[rt][rg];
          out[(size_t)s * ATTN_K + head * 64 + dn * 16 + lr] = f2bf(val);
        }
  }
}

extern "C" void kernel_launch(void* const* d_in, const int* in_sizes, int n_in,
                              void* d_out, int out_size, void* d_ws, size_t ws_size,
                              hipStream_t stream) {
  const float* hs = (const float*)d_in[0];
  const int* pos = (const int*)d_in[1];
  const float* wqkv = (const float*)d_in[2];
  const float* bqkv = (const float*)d_in[3];
  const float* wo = (const float*)d_in[4];
  const float* bo = (const float*)d_in[5];
  const float* sinks = (const float*)d_in[6];
  float* out = (float*)d_out;

  char* ws = (char*)d_ws;
  u16* qkvb = (u16*)(ws + 0);               // 2048*5120*2 = 20,971,520 (bf16, un-roped)
  u16* hsb = (u16*)(ws + 41943040);         // 2048*2944*2 = 12,058,624
  u16* wqkvT = (u16*)(ws + 54001664);       // 5120*2944*2 = 30,146,560 -> ends 84,148,224
  u16* attnb = (u16*)(ws + 41943040);       // 2048*4096*2 (aliases dead hsb/wqkvT)
  u16* woT = (u16*)(ws + 84148224);         // 2944*4096*2 = 24,117,248 -> ends 108,265,472
  float2* tab = (float2*)(ws + 108265472);  // 2048*32*8   = 524,288

  k_prep<<<32640, 256, 0, stream>>>(pos, tab, hs, hsb, wqkv, wqkvT, wo, woT);
  k_gemm1<<<512, 256, 0, stream>>>(hsb, wqkvT, bqkv, qkvb);
  k_attn<<<dim3(32, 8), 512, 0, stream>>>(qkvb, sinks, tab, attnb);
  k_gemm2<<<480, 256, 0, stream>>>(attnb, woT, bo, out);
}